// Round 1
// baseline (989.019 us; speedup 1.0000x reference)
//
#include <hip/hip_runtime.h>
#include <math.h>

// ---- problem constants ----
#define DIMC   256
#define HID    680          // int(256*2.66)
#define CHN    1360         // 2*HID
#define K2     9
#define HP     14
#define WP     14
#define P      196          // HP*WP
#define POSI   4
#define INTER  64
#define BATCH  64
#define OUTCH  12240        // CHN*K2
#define EPSLN  1e-5f

// ---- workspace layout (floats) ----
#define OFS_A    0
#define OFS_V    12544
#define OFS_WGT  25088
#define OFS_H1   (OFS_WGT + OUTCH*P)          // wgt: 2,399,040
#define OFS_HG   (OFS_H1 + (size_t)BATCH*CHN*P) // h1: 17,059,840
// total = 28,013,888 floats = ~112 MB

__device__ __forceinline__ void block_reduce2(float& s, float& ss, float* red, int tid, int nthreads) {
    #pragma unroll
    for (int off = 32; off > 0; off >>= 1) {
        s  += __shfl_down(s, off);
        ss += __shfl_down(ss, off);
    }
    int wid = tid >> 6, nw = nthreads >> 6;
    if ((tid & 63) == 0) { red[wid*2] = s; red[wid*2+1] = ss; }
    __syncthreads();
    if (tid == 0) {
        float S = 0.f, SS = 0.f;
        for (int i = 0; i < nw; i++) { S += red[i*2]; SS += red[i*2+1]; }
        red[0] = S; red[1] = SS;
    }
    __syncthreads();
    s = red[0]; ss = red[1];
}

// stage0: conv(posi_map, w0, pad1) -> LN -> relu   (one block)
__global__ __launch_bounds__(256) void k_stage0(const float* __restrict__ posi,
                                                const float* __restrict__ w0,
                                                const float* __restrict__ g0,
                                                const float* __restrict__ b0,
                                                float* __restrict__ a_out) {
    __shared__ __align__(16) float ppad[POSI][16][16];
    __shared__ __align__(16) float t[INTER * P];
    __shared__ float red[64];
    int tid = threadIdx.x;
    for (int i = tid; i < POSI * 256; i += 256) {
        int c = i >> 8, r = i & 255, ly = r >> 4, lx = r & 15;
        float v = 0.f;
        if (ly >= 1 && ly <= HP && lx >= 1 && lx <= WP) v = posi[c*P + (ly-1)*WP + (lx-1)];
        ppad[c][ly][lx] = v;
    }
    __syncthreads();
    float s = 0.f, ss = 0.f;
    for (int idx = tid; idx < INTER * P; idx += 256) {
        int c = idx / P, p = idx - c*P, y = p / WP, x = p - (p/WP)*WP;
        float acc = 0.f;
        #pragma unroll
        for (int ci = 0; ci < POSI; ci++)
            #pragma unroll
            for (int dy = 0; dy < 3; dy++)
                #pragma unroll
                for (int dx = 0; dx < 3; dx++)
                    acc += w0[((c*POSI + ci)*3 + dy)*3 + dx] * ppad[ci][y+dy][x+dx];
        t[idx] = acc; s += acc; ss += acc*acc;
    }
    block_reduce2(s, ss, red, tid, 256);
    float mu = s / (float)(INTER*P);
    float var = ss / (float)(INTER*P) - mu*mu;
    float rstd = rsqrtf(var + EPSLN);
    for (int idx = tid; idx < INTER * P; idx += 256) {
        float v = (t[idx] - mu) * rstd * g0[idx] + b0[idx];
        a_out[idx] = v > 0.f ? v : 0.f;
    }
}

// 64ch -> 64ch 3x3 conv, pad 1 (49 blocks x 256 = 12544 outputs)
__global__ __launch_bounds__(256) void k_conv64(const float* __restrict__ a,
                                                const float* __restrict__ w,
                                                float* __restrict__ v) {
    __shared__ __align__(16) float as[INTER][16][16];
    int tid = threadIdx.x;
    for (int i = tid; i < INTER * 256; i += 256) {
        int c = i >> 8, r = i & 255, ly = r >> 4, lx = r & 15;
        float val = 0.f;
        if (ly >= 1 && ly <= HP && lx >= 1 && lx <= WP) val = a[c*P + (ly-1)*WP + (lx-1)];
        as[c][ly][lx] = val;
    }
    __syncthreads();
    int idx = blockIdx.x * 256 + tid;
    int c = idx / P, p = idx - c*P, y = p / WP, x = p - (p/WP)*WP;
    float acc = 0.f;
    for (int ci = 0; ci < INTER; ci++) {
        const float* wr = w + (c*INTER + ci)*9;
        acc += wr[0]*as[ci][y  ][x] + wr[1]*as[ci][y  ][x+1] + wr[2]*as[ci][y  ][x+2]
             + wr[3]*as[ci][y+1][x] + wr[4]*as[ci][y+1][x+1] + wr[5]*as[ci][y+1][x+2]
             + wr[6]*as[ci][y+2][x] + wr[7]*as[ci][y+2][x+1] + wr[8]*as[ci][y+2][x+2];
    }
    v[idx] = acc;
}

// full-tensor LN (mean/var over all 12544) + affine + relu (one block)
__global__ __launch_bounds__(1024) void k_lnrelu(const float* __restrict__ v,
                                                 const float* __restrict__ g,
                                                 const float* __restrict__ b,
                                                 float* __restrict__ a) {
    __shared__ float red[64];
    int tid = threadIdx.x;
    float s = 0.f, ss = 0.f;
    float vals[13];
    int cnt = 0;
    for (int idx = tid; idx < INTER * P; idx += 1024) {
        float x = v[idx]; vals[cnt++] = x; s += x; ss += x*x;
    }
    block_reduce2(s, ss, red, tid, 1024);
    float mu = s / (float)(INTER*P);
    float var = ss / (float)(INTER*P) - mu*mu;
    float rstd = rsqrtf(var + EPSLN);
    cnt = 0;
    for (int idx = tid; idx < INTER * P; idx += 1024) {
        float x = (vals[cnt++] - mu) * rstd * g[idx] + b[idx];
        a[idx] = x > 0.f ? x : 0.f;
    }
}

// final conv of weight net: 64ch -> 12240ch, 3x3 pad1.  block: 196 px x 16 oc
__global__ __launch_bounds__(256) void k_convf(const float* __restrict__ a,
                                               const float* __restrict__ wf,
                                               float* __restrict__ wgt) {
    __shared__ __align__(16) float as[INTER][16][16];
    int tid = threadIdx.x;
    for (int i = tid; i < INTER * 256; i += 256) {
        int c = i >> 8, r = i & 255, ly = r >> 4, lx = r & 15;
        float val = 0.f;
        if (ly >= 1 && ly <= HP && lx >= 1 && lx <= WP) val = a[c*P + (ly-1)*WP + (lx-1)];
        as[c][ly][lx] = val;
    }
    __syncthreads();
    int oc0 = blockIdx.x * 16;
    int p = tid;
    if (p < P) {
        int y = p / WP, x = p - (p/WP)*WP;
        float acc[16];
        #pragma unroll
        for (int o = 0; o < 16; o++) acc[o] = 0.f;
        for (int ci = 0; ci < INTER; ci++) {
            float q0 = as[ci][y  ][x], q1 = as[ci][y  ][x+1], q2 = as[ci][y  ][x+2];
            float q3 = as[ci][y+1][x], q4 = as[ci][y+1][x+1], q5 = as[ci][y+1][x+2];
            float q6 = as[ci][y+2][x], q7 = as[ci][y+2][x+1], q8 = as[ci][y+2][x+2];
            #pragma unroll
            for (int o = 0; o < 16; o++) {
                const float* w = wf + ((size_t)(oc0 + o)*INTER + ci)*9;  // wave-uniform -> s_load
                acc[o] += w[0]*q0 + w[1]*q1 + w[2]*q2 + w[3]*q3 + w[4]*q4
                        + w[5]*q5 + w[6]*q6 + w[7]*q7 + w[8]*q8;
            }
        }
        #pragma unroll
        for (int o = 0; o < 16; o++) wgt[(size_t)(oc0 + o)*P + p] = acc[o];
    }
}

// Y[b][o][p] = sum_c W[o][c] * X[b][c][p].  Tile: 40 o x 196 p, K-chunks of 32.
// threads: px = tid%49 (4 consecutive p), oy = tid/49 (5 groups of 8 o)
__global__ __launch_bounds__(256) void k_gemm(const float* __restrict__ W,
                                              const float* __restrict__ X,
                                              float* __restrict__ Y,
                                              int M, int Kd) {
    __shared__ __align__(16) float Xs[32][196];
    __shared__ __align__(16) float Ws[32][40];
    int tid = threadIdx.x;
    int b = blockIdx.y;
    int o0 = blockIdx.x * 40;
    int px = tid % 49, oy = tid / 49;   // oy==5 -> inactive for compute
    float4 acc[8];
    #pragma unroll
    for (int j = 0; j < 8; j++) acc[j] = make_float4(0.f, 0.f, 0.f, 0.f);
    const float* Xb = X + (size_t)b * Kd * P;
    int nch = (Kd + 31) / 32;
    for (int ch = 0; ch < nch; ch++) {
        int c0 = ch * 32;
        for (int i = tid; i < 32 * 196; i += 256) {
            int k = i / 196, p = i - k*196;
            int c = c0 + k;
            Xs[k][p] = (c < Kd) ? Xb[(size_t)c*P + p] : 0.f;
        }
        for (int i = tid; i < 40 * 32; i += 256) {
            int j = i >> 5, k = i & 31;       // consecutive tid -> consecutive k (coalesced)
            int o = o0 + j, c = c0 + k;
            Ws[k][j] = (o < M && c < Kd) ? W[(size_t)o*Kd + c] : 0.f;
        }
        __syncthreads();
        if (oy < 5) {
            #pragma unroll
            for (int k = 0; k < 32; k++) {
                float4 xv = *(const float4*)&Xs[k][px*4];
                float4 wa = *(const float4*)&Ws[k][oy*8];
                float4 wb = *(const float4*)&Ws[k][oy*8 + 4];
                acc[0].x += wa.x*xv.x; acc[0].y += wa.x*xv.y; acc[0].z += wa.x*xv.z; acc[0].w += wa.x*xv.w;
                acc[1].x += wa.y*xv.x; acc[1].y += wa.y*xv.y; acc[1].z += wa.y*xv.z; acc[1].w += wa.y*xv.w;
                acc[2].x += wa.z*xv.x; acc[2].y += wa.z*xv.y; acc[2].z += wa.z*xv.z; acc[2].w += wa.z*xv.w;
                acc[3].x += wa.w*xv.x; acc[3].y += wa.w*xv.y; acc[3].z += wa.w*xv.z; acc[3].w += wa.w*xv.w;
                acc[4].x += wb.x*xv.x; acc[4].y += wb.x*xv.y; acc[4].z += wb.x*xv.z; acc[4].w += wb.x*xv.w;
                acc[5].x += wb.y*xv.x; acc[5].y += wb.y*xv.y; acc[5].z += wb.y*xv.z; acc[5].w += wb.y*xv.w;
                acc[6].x += wb.z*xv.x; acc[6].y += wb.z*xv.y; acc[6].z += wb.z*xv.z; acc[6].w += wb.z*xv.w;
                acc[7].x += wb.w*xv.x; acc[7].y += wb.w*xv.y; acc[7].z += wb.w*xv.z; acc[7].w += wb.w*xv.w;
            }
        }
        __syncthreads();
    }
    if (oy < 5) {
        #pragma unroll
        for (int j = 0; j < 8; j++) {
            int o = o0 + oy*8 + j;
            if (o < M) *(float4*)&Y[((size_t)b*M + o)*P + px*4] = acc[j];
        }
    }
}

// fused tvconv (per-pixel 3x3 weights) + GLU(exact gelu). grid (ch=680, b=64)
__global__ __launch_bounds__(256) void k_tvgelu(const float* __restrict__ h1,
                                                const float* __restrict__ wgt,
                                                float* __restrict__ hg) {
    __shared__ __align__(16) float hs[2][16][16];
    int tid = threadIdx.x;
    int chn = blockIdx.x;
    int b = blockIdx.y;
    const float* p1 = h1 + ((size_t)b*CHN + chn) * P;
    const float* p2 = h1 + ((size_t)b*CHN + chn + HID) * P;
    {
        int ly = tid >> 4, lx = tid & 15;
        float v1 = 0.f, v2 = 0.f;
        if (ly >= 1 && ly <= HP && lx >= 1 && lx <= WP) {
            int q = (ly-1)*WP + (lx-1);
            v1 = p1[q]; v2 = p2[q];
        }
        hs[0][ly][lx] = v1; hs[1][ly][lx] = v2;
    }
    __syncthreads();
    if (tid < P) {
        int y = tid / WP, x = tid - (tid/WP)*WP;
        float s1 = 0.f, s2 = 0.f;
        #pragma unroll
        for (int k = 0; k < 9; k++) {
            int dy = k / 3, dx = k - (k/3)*3;
            float w1v = wgt[((size_t)chn*9 + k)*P + tid];
            float w2v = wgt[((size_t)(chn + HID)*9 + k)*P + tid];
            s1 += w1v * hs[0][y+dy][x+dx];
            s2 += w2v * hs[1][y+dy][x+dx];
        }
        float gl = 0.5f * s1 * (1.f + erff(s1 * 0.70710678118654752f));
        hg[((size_t)b*HID + chn)*P + tid] = gl * s2;
    }
}

extern "C" void kernel_launch(void* const* d_in, const int* in_sizes, int n_in,
                              void* d_out, int out_size, void* d_ws, size_t ws_size,
                              hipStream_t stream) {
    (void)in_sizes; (void)n_in; (void)out_size; (void)ws_size;
    const float* x     = (const float*)d_in[0];
    const float* W_in  = (const float*)d_in[1];
    const float* posi  = (const float*)d_in[2];
    const float* w0    = (const float*)d_in[3];
    const float* g0    = (const float*)d_in[4];
    const float* b0    = (const float*)d_in[5];
    const float* w1    = (const float*)d_in[6];
    const float* g1    = (const float*)d_in[7];
    const float* b1    = (const float*)d_in[8];
    const float* w2    = (const float*)d_in[9];
    const float* g2    = (const float*)d_in[10];
    const float* b2    = (const float*)d_in[11];
    const float* wf    = (const float*)d_in[12];
    const float* W_out = (const float*)d_in[13];
    float* out = (float*)d_out;
    float* ws  = (float*)d_ws;

    float* a_buf = ws + OFS_A;
    float* v_buf = ws + OFS_V;
    float* wgt   = ws + OFS_WGT;
    float* h1    = ws + OFS_H1;
    float* hg    = ws + OFS_HG;

    // weight-generator network (tiny, serial chain)
    k_stage0<<<1, 256, 0, stream>>>(posi, w0, g0, b0, a_buf);
    k_conv64<<<49, 256, 0, stream>>>(a_buf, w1, v_buf);
    k_lnrelu<<<1, 1024, 0, stream>>>(v_buf, g1, b1, a_buf);
    k_conv64<<<49, 256, 0, stream>>>(a_buf, w2, v_buf);
    k_lnrelu<<<1, 1024, 0, stream>>>(v_buf, g2, b2, a_buf);
    k_convf<<<765, 256, 0, stream>>>(a_buf, wf, wgt);

    // main path
    k_gemm<<<dim3(34, BATCH), 256, 0, stream>>>(W_in, x, h1, CHN, DIMC);      // h1 = W_in @ x
    k_tvgelu<<<dim3(HID, BATCH), 256, 0, stream>>>(h1, wgt, hg);              // tvconv + gelu*gate
    k_gemm<<<dim3(7, BATCH), 256, 0, stream>>>(W_out, hg, out, DIMC, HID);    // out = W_out @ hg
}

// Round 2
// 584.838 us; speedup vs baseline: 1.6911x; 1.6911x over previous
//
#include <hip/hip_runtime.h>
#include <math.h>

// ---- problem constants ----
#define DIMC   256
#define HID    680
#define CHN    1360
#define HP     14
#define WP     14
#define P      196
#define POSI   4
#define INTER  64
#define BATCH  64
#define KPAD   704          // 680 padded to 22*32 for MFMA k-steps
#define EPSLN  1e-5f

typedef __attribute__((ext_vector_type(8))) short short8;
typedef __attribute__((ext_vector_type(4))) short short4v;
typedef __attribute__((ext_vector_type(4))) float f32x4;

// ---- workspace layout (bytes) ----
#define OFS_WBIN  0u                  // 1360*256*2   = 696320
#define OFS_WBOUT 696320u             // 256*704*2    = 360448
#define OFS_XT    1056768u            // 64*196*256*2 = 6422528
#define OFS_ABUF  7479296u            // 12544*4
#define OFS_VBUF  7529472u            // 12544*4
#define OFS_WGTT  7579648u            // 196*9*1360*2 = 4798080
#define OFS_H1T   12377728u           // 64*196*1360*2 = 34127872
#define OFS_HGT   46505600u           // 64*196*704*2  = 17661952  (end ~64.2MB)

__device__ __forceinline__ unsigned short f2bf(float f) {
    union { float f; unsigned u; } v; v.f = f;
    unsigned u = v.u;
    return (unsigned short)((u + 0x7FFFu + ((u >> 16) & 1u)) >> 16);   // RNE
}
__device__ __forceinline__ float bf2f(unsigned short h) {
    union { unsigned u; float f; } v; v.u = ((unsigned)h) << 16; return v.f;
}

// ---------------- small casts ----------------
__global__ void k_cast_win(const float* __restrict__ W, unsigned short* __restrict__ Wb) {
    int i = blockIdx.x * 256 + threadIdx.x;
    if (i < CHN * DIMC) Wb[i] = f2bf(W[i]);
}
__global__ void k_cast_wout(const float* __restrict__ W, unsigned short* __restrict__ Wb) {
    int i = blockIdx.x * 256 + threadIdx.x;
    if (i < DIMC * KPAD) {
        int o = i / KPAD, k = i - o * KPAD;
        Wb[i] = f2bf(k < HID ? W[o * HID + k] : 0.f);
    }
}
// x [64][256][196] f32 -> Xt [64][196][256] bf16 (LDS transpose, padded stride)
__global__ __launch_bounds__(256) void k_xt(const float* __restrict__ x,
                                            unsigned short* __restrict__ Xt) {
    __shared__ float xs[32][197];
    int b = blockIdx.y, c0 = blockIdx.x * 32, tid = threadIdx.x;
    for (int i = tid; i < 32 * P; i += 256) {
        int ci = i / P, pp = i - ci * P;
        xs[ci][pp] = x[((size_t)b * DIMC + c0 + ci) * P + pp];
    }
    __syncthreads();
    for (int j = tid; j < P * 32; j += 256) {
        int ci = j & 31, pp = j >> 5;
        Xt[((size_t)b * P + pp) * DIMC + c0 + ci] = f2bf(xs[ci][pp]);
    }
}

// ---------------- weight-generator net (unchanged structure) ----------------
__device__ __forceinline__ void block_reduce2(float& s, float& ss, float* red, int tid, int nthreads) {
    #pragma unroll
    for (int off = 32; off > 0; off >>= 1) {
        s  += __shfl_down(s, off);
        ss += __shfl_down(ss, off);
    }
    int wid = tid >> 6, nw = nthreads >> 6;
    if ((tid & 63) == 0) { red[wid*2] = s; red[wid*2+1] = ss; }
    __syncthreads();
    if (tid == 0) {
        float S = 0.f, SS = 0.f;
        for (int i = 0; i < nw; i++) { S += red[i*2]; SS += red[i*2+1]; }
        red[0] = S; red[1] = SS;
    }
    __syncthreads();
    s = red[0]; ss = red[1];
}

__global__ __launch_bounds__(256) void k_stage0(const float* __restrict__ posi,
                                                const float* __restrict__ w0,
                                                const float* __restrict__ g0,
                                                const float* __restrict__ b0,
                                                float* __restrict__ a_out) {
    __shared__ __align__(16) float ppad[POSI][16][16];
    __shared__ __align__(16) float t[INTER * P];
    __shared__ float red[64];
    int tid = threadIdx.x;
    for (int i = tid; i < POSI * 256; i += 256) {
        int c = i >> 8, r = i & 255, ly = r >> 4, lx = r & 15;
        float v = 0.f;
        if (ly >= 1 && ly <= HP && lx >= 1 && lx <= WP) v = posi[c*P + (ly-1)*WP + (lx-1)];
        ppad[c][ly][lx] = v;
    }
    __syncthreads();
    float s = 0.f, ss = 0.f;
    for (int idx = tid; idx < INTER * P; idx += 256) {
        int c = idx / P, p = idx - c*P, y = p / WP, x = p - (p/WP)*WP;
        float acc = 0.f;
        #pragma unroll
        for (int ci = 0; ci < POSI; ci++)
            #pragma unroll
            for (int dy = 0; dy < 3; dy++)
                #pragma unroll
                for (int dx = 0; dx < 3; dx++)
                    acc += w0[((c*POSI + ci)*3 + dy)*3 + dx] * ppad[ci][y+dy][x+dx];
        t[idx] = acc; s += acc; ss += acc*acc;
    }
    block_reduce2(s, ss, red, tid, 256);
    float mu = s / (float)(INTER*P);
    float var = ss / (float)(INTER*P) - mu*mu;
    float rstd = rsqrtf(var + EPSLN);
    for (int idx = tid; idx < INTER * P; idx += 256) {
        float v = (t[idx] - mu) * rstd * g0[idx] + b0[idx];
        a_out[idx] = v > 0.f ? v : 0.f;
    }
}

__global__ __launch_bounds__(256) void k_conv64(const float* __restrict__ a,
                                                const float* __restrict__ w,
                                                float* __restrict__ v) {
    __shared__ __align__(16) float as[INTER][16][16];
    int tid = threadIdx.x;
    for (int i = tid; i < INTER * 256; i += 256) {
        int c = i >> 8, r = i & 255, ly = r >> 4, lx = r & 15;
        float val = 0.f;
        if (ly >= 1 && ly <= HP && lx >= 1 && lx <= WP) val = a[c*P + (ly-1)*WP + (lx-1)];
        as[c][ly][lx] = val;
    }
    __syncthreads();
    int idx = blockIdx.x * 256 + tid;
    int c = idx / P, p = idx - c*P, y = p / WP, x = p - (p/WP)*WP;
    float acc = 0.f;
    for (int ci = 0; ci < INTER; ci++) {
        const float* wr = w + (c*INTER + ci)*9;
        acc += wr[0]*as[ci][y  ][x] + wr[1]*as[ci][y  ][x+1] + wr[2]*as[ci][y  ][x+2]
             + wr[3]*as[ci][y+1][x] + wr[4]*as[ci][y+1][x+1] + wr[5]*as[ci][y+1][x+2]
             + wr[6]*as[ci][y+2][x] + wr[7]*as[ci][y+2][x+1] + wr[8]*as[ci][y+2][x+2];
    }
    v[idx] = acc;
}

__global__ __launch_bounds__(1024) void k_lnrelu(const float* __restrict__ v,
                                                 const float* __restrict__ g,
                                                 const float* __restrict__ b,
                                                 float* __restrict__ a) {
    __shared__ float red[64];
    int tid = threadIdx.x;
    float s = 0.f, ss = 0.f;
    float vals[13];
    int cnt = 0;
    for (int idx = tid; idx < INTER * P; idx += 1024) {
        float x = v[idx]; vals[cnt++] = x; s += x; ss += x*x;
    }
    block_reduce2(s, ss, red, tid, 1024);
    float mu = s / (float)(INTER*P);
    float var = ss / (float)(INTER*P) - mu*mu;
    float rstd = rsqrtf(var + EPSLN);
    cnt = 0;
    for (int idx = tid; idx < INTER * P; idx += 1024) {
        float x = (vals[cnt++] - mu) * rstd * g[idx] + b[idx];
        a[idx] = x > 0.f ? x : 0.f;
    }
}

// final conv: 64ch -> 12240ch. block = (ch-tile of 16, fixed k). writes bf16 wgtT[p][k][ch]
__global__ __launch_bounds__(256) void k_convf(const float* __restrict__ a,
                                               const float* __restrict__ wf,
                                               unsigned short* __restrict__ wgtT) {
    __shared__ __align__(16) float as[INTER][16][16];
    __shared__ float accs[16][197];
    int tid = threadIdx.x;
    for (int i = tid; i < INTER * 256; i += 256) {
        int c = i >> 8, r = i & 255, ly = r >> 4, lx = r & 15;
        float val = 0.f;
        if (ly >= 1 && ly <= HP && lx >= 1 && lx <= WP) val = a[c*P + (ly-1)*WP + (lx-1)];
        as[c][ly][lx] = val;
    }
    __syncthreads();
    int ch0 = blockIdx.x * 16;      // 85 tiles of 16 channels (of 1360)
    int kk  = blockIdx.y;           // 0..8
    int p = tid;
    if (p < P) {
        int y = p / WP, x = p - (p/WP)*WP;
        float acc[16];
        #pragma unroll
        for (int o = 0; o < 16; o++) acc[o] = 0.f;
        for (int ci = 0; ci < INTER; ci++) {
            float q0 = as[ci][y  ][x], q1 = as[ci][y  ][x+1], q2 = as[ci][y  ][x+2];
            float q3 = as[ci][y+1][x], q4 = as[ci][y+1][x+1], q5 = as[ci][y+1][x+2];
            float q6 = as[ci][y+2][x], q7 = as[ci][y+2][x+1], q8 = as[ci][y+2][x+2];
            #pragma unroll
            for (int o = 0; o < 16; o++) {
                int oc = (ch0 + o) * 9 + kk;                 // conv output channel
                const float* w = wf + ((size_t)oc * INTER + ci) * 9;  // wave-uniform
                acc[o] += w[0]*q0 + w[1]*q1 + w[2]*q2 + w[3]*q3 + w[4]*q4
                        + w[5]*q5 + w[6]*q6 + w[7]*q7 + w[8]*q8;
            }
        }
        #pragma unroll
        for (int o = 0; o < 16; o++) accs[o][p] = acc[o];
    }
    __syncthreads();
    for (int j = tid; j < 16 * P; j += 256) {
        int chi = j & 15, pp = j >> 4;
        wgtT[((size_t)pp * 9 + kk) * CHN + ch0 + chi] = f2bf(accs[chi][pp]);
    }
}

// ---------------- MFMA GEMM 1: h1t[b][p][o] = sum_c W_in[o][c] x[b][c][p] ----------------
// A[m=lane&15][k=quad*8+j] from Wb rows; B[k=quad*8+j][n=lane&15] from Xt rows.
// C/D: col=lane&15 (p), row=quad*4+reg (o).
__global__ __launch_bounds__(256) void k_gemm_in(const unsigned short* __restrict__ Wb,
                                                 const unsigned short* __restrict__ Xt,
                                                 unsigned short* __restrict__ h1t) {
    int tid = threadIdx.x;
    int w = tid >> 6, l = tid & 63;
    int quad = l >> 4, c16 = l & 15;
    int b = blockIdx.y;
    int o0 = blockIdx.x * 64 + w * 16;
    if (o0 >= CHN) return;                       // waves independent, no barriers
    f32x4 acc[13];
    #pragma unroll
    for (int f = 0; f < 13; f++) acc[f] = (f32x4)0.f;
    const unsigned short* Arow = Wb + (size_t)(o0 + c16) * DIMC + quad * 8;
    const unsigned short* Xb   = Xt + (size_t)b * P * DIMC + quad * 8;
    #pragma unroll
    for (int kk = 0; kk < 8; kk++) {
        int k0 = kk * 32;
        short8 af = *(const short8*)(Arow + k0);
        #pragma unroll
        for (int f = 0; f < 13; f++) {
            int p = f * 16 + c16;
            short8 bf = (short8)0;
            if (p < P) bf = *(const short8*)(Xb + (size_t)p * DIMC + k0);
            acc[f] = __builtin_amdgcn_mfma_f32_16x16x32_bf16(af, bf, acc[f], 0, 0, 0);
        }
    }
    #pragma unroll
    for (int f = 0; f < 13; f++) {
        int p = f * 16 + c16;
        if (p < P) {
            short4v sv;
            sv[0] = (short)f2bf(acc[f][0]);
            sv[1] = (short)f2bf(acc[f][1]);
            sv[2] = (short)f2bf(acc[f][2]);
            sv[3] = (short)f2bf(acc[f][3]);
            *(short4v*)(h1t + ((size_t)b * P + p) * CHN + o0 + quad * 4) = sv;
        }
    }
}

// ---------------- fused tvconv + gelu-gate, transposed layouts, no LDS ----------------
__global__ __launch_bounds__(256) void k_tvg(const unsigned short* __restrict__ h1t,
                                             const unsigned short* __restrict__ wgtT,
                                             unsigned short* __restrict__ hgt) {
    int p = blockIdx.x, b = blockIdx.y, tid = threadIdx.x;
    int y = p / WP, x = p - (p / WP) * WP;
    int pn[9]; bool pv[9];
    #pragma unroll
    for (int k = 0; k < 9; k++) {
        int yy = y + k / 3 - 1, xx = x + (k % 3) - 1;
        pv[k] = (yy >= 0 && yy < HP && xx >= 0 && xx < WP);
        pn[k] = pv[k] ? yy * WP + xx : 0;
    }
    const unsigned short* wrow = wgtT + (size_t)p * 9 * CHN;
    const unsigned short* hb   = h1t + (size_t)b * P * CHN;
    unsigned short* orow = hgt + ((size_t)b * P + p) * KPAD;
    for (int c = tid; c < HID; c += 256) {
        float s1 = 0.f, s2 = 0.f;
        #pragma unroll
        for (int k = 0; k < 9; k++) {
            if (!pv[k]) continue;                       // block-uniform branch
            const unsigned short* hr = hb + (size_t)pn[k] * CHN;
            s1 += bf2f(wrow[k * CHN + c])       * bf2f(hr[c]);
            s2 += bf2f(wrow[k * CHN + HID + c]) * bf2f(hr[HID + c]);
        }
        float gl = 0.5f * s1 * (1.f + erff(s1 * 0.70710678118654752f));
        orow[c] = f2bf(gl * s2);
    }
    if (tid < KPAD - HID) orow[HID + tid] = 0;          // zero the k-pad
}

// ---------------- MFMA GEMM 2: out[b][o][p] = sum_c W_out[o][c] hg[b][c][p] ----------------
__global__ __launch_bounds__(256) void k_gemm_out(const unsigned short* __restrict__ Wb,
                                                  const unsigned short* __restrict__ hgt,
                                                  float* __restrict__ out) {
    int tid = threadIdx.x;
    int w = tid >> 6, l = tid & 63;
    int quad = l >> 4, c16 = l & 15;
    int b = blockIdx.y;
    int o0 = blockIdx.x * 64 + w * 16;
    f32x4 acc[13];
    #pragma unroll
    for (int f = 0; f < 13; f++) acc[f] = (f32x4)0.f;
    const unsigned short* Arow = Wb + (size_t)(o0 + c16) * KPAD + quad * 8;
    const unsigned short* Hb   = hgt + (size_t)b * P * KPAD + quad * 8;
    for (int kk = 0; kk < 22; kk++) {
        int k0 = kk * 32;
        short8 af = *(const short8*)(Arow + k0);
        #pragma unroll
        for (int f = 0; f < 13; f++) {
            int p = f * 16 + c16;
            short8 bf = (short8)0;
            if (p < P) bf = *(const short8*)(Hb + (size_t)p * KPAD + k0);
            acc[f] = __builtin_amdgcn_mfma_f32_16x16x32_bf16(af, bf, acc[f], 0, 0, 0);
        }
    }
    #pragma unroll
    for (int f = 0; f < 13; f++) {
        int p = f * 16 + c16;
        if (p < P) {
            #pragma unroll
            for (int r = 0; r < 4; r++) {
                int o = o0 + quad * 4 + r;
                out[((size_t)b * DIMC + o) * P + p] = acc[f][r];
            }
        }
    }
}

extern "C" void kernel_launch(void* const* d_in, const int* in_sizes, int n_in,
                              void* d_out, int out_size, void* d_ws, size_t ws_size,
                              hipStream_t stream) {
    (void)in_sizes; (void)n_in; (void)out_size; (void)ws_size;
    const float* x     = (const float*)d_in[0];
    const float* W_in  = (const float*)d_in[1];
    const float* posi  = (const float*)d_in[2];
    const float* w0    = (const float*)d_in[3];
    const float* g0    = (const float*)d_in[4];
    const float* b0    = (const float*)d_in[5];
    const float* w1    = (const float*)d_in[6];
    const float* g1    = (const float*)d_in[7];
    const float* b1    = (const float*)d_in[8];
    const float* w2    = (const float*)d_in[9];
    const float* g2    = (const float*)d_in[10];
    const float* b2    = (const float*)d_in[11];
    const float* wf    = (const float*)d_in[12];
    const float* W_out = (const float*)d_in[13];
    float* out = (float*)d_out;
    char* ws = (char*)d_ws;

    unsigned short* Wbin  = (unsigned short*)(ws + OFS_WBIN);
    unsigned short* Wbout = (unsigned short*)(ws + OFS_WBOUT);
    unsigned short* Xt    = (unsigned short*)(ws + OFS_XT);
    float*          a_buf = (float*)(ws + OFS_ABUF);
    float*          v_buf = (float*)(ws + OFS_VBUF);
    unsigned short* wgtT  = (unsigned short*)(ws + OFS_WGTT);
    unsigned short* h1t   = (unsigned short*)(ws + OFS_H1T);
    unsigned short* hgt   = (unsigned short*)(ws + OFS_HGT);

    // casts / transposes
    k_cast_win <<<(CHN*DIMC + 255)/256, 256, 0, stream>>>(W_in, Wbin);
    k_cast_wout<<<(DIMC*KPAD + 255)/256, 256, 0, stream>>>(W_out, Wbout);
    k_xt       <<<dim3(DIMC/32, BATCH), 256, 0, stream>>>(x, Xt);

    // weight-generator network
    k_stage0<<<1, 256, 0, stream>>>(posi, w0, g0, b0, a_buf);
    k_conv64<<<49, 256, 0, stream>>>(a_buf, w1, v_buf);
    k_lnrelu<<<1, 1024, 0, stream>>>(v_buf, g1, b1, a_buf);
    k_conv64<<<49, 256, 0, stream>>>(a_buf, w2, v_buf);
    k_lnrelu<<<1, 1024, 0, stream>>>(v_buf, g2, b2, a_buf);
    k_convf <<<dim3(85, 9), 256, 0, stream>>>(a_buf, wf, wgtT);

    // main path (MFMA)
    k_gemm_in <<<dim3(22, BATCH), 256, 0, stream>>>(Wbin, Xt, h1t);
    k_tvg     <<<dim3(P, BATCH), 256, 0, stream>>>(h1t, wgtT, hgt);
    k_gemm_out<<<dim3(4, BATCH), 256, 0, stream>>>(Wbout, hgt, out);
}

// Round 3
// 459.737 us; speedup vs baseline: 2.1513x; 1.2721x over previous
//
#include <hip/hip_runtime.h>
#include <math.h>

// ---- problem constants ----
#define DIMC   256
#define HID    680
#define CHN    1360
#define HP     14
#define WP     14
#define P      196
#define POSI   4
#define INTER  64
#define BATCH  64
#define KPAD   704          // 680 padded to 22*32 for MFMA k-steps
#define OUTCH  12240        // CHN*9
#define KIM    576          // INTER*9 im2col depth (= 18*32)
#define EPSLN  1e-5f

typedef __attribute__((ext_vector_type(8))) short short8;
typedef __attribute__((ext_vector_type(4))) short short4v;
typedef __attribute__((ext_vector_type(4))) float f32x4;

// ---- workspace layout (bytes) ----
#define OFS_WBIN  0u                  // 1360*256*2   = 696320
#define OFS_WBOUT 696320u             // 256*704*2    = 360448
#define OFS_XT    1056768u            // 64*196*256*2 = 6422528
#define OFS_ABUF  7479296u            // 12544*4
#define OFS_VBUF  7529472u            // 12544*4
#define OFS_WGTT  7579648u            // 196*9*1360*2 = 4798080
#define OFS_H1T   12377728u           // 64*196*1360*2 = 34127872
#define OFS_HGT   46505600u           // 64*196*704*2  = 17661952
#define OFS_WFB   64167552u           // 12240*576*2   = 14100480
#define OFS_IMC   78268032u           // 196*576*2     = 225792   (end ~78.5MB)

__device__ __forceinline__ unsigned short f2bf(float f) {
    union { float f; unsigned u; } v; v.f = f;
    unsigned u = v.u;
    return (unsigned short)((u + 0x7FFFu + ((u >> 16) & 1u)) >> 16);   // RNE
}
__device__ __forceinline__ float bf2f(unsigned short h) {
    union { unsigned u; float f; } v; v.u = ((unsigned)h) << 16; return v.f;
}

// ---------------- small casts ----------------
__global__ void k_cast_win(const float* __restrict__ W, unsigned short* __restrict__ Wb) {
    int i = blockIdx.x * 256 + threadIdx.x;
    if (i < CHN * DIMC) Wb[i] = f2bf(W[i]);
}
__global__ void k_cast_wout(const float* __restrict__ W, unsigned short* __restrict__ Wb) {
    int i = blockIdx.x * 256 + threadIdx.x;
    if (i < DIMC * KPAD) {
        int o = i / KPAD, k = i - o * KPAD;
        Wb[i] = f2bf(k < HID ? W[o * HID + k] : 0.f);
    }
}
// wf f32 [12240*576] -> bf16, 4 elems/thread
__global__ void k_cast_wf(const float* __restrict__ wf, unsigned short* __restrict__ wfb) {
    int i = (blockIdx.x * 256 + threadIdx.x) * 4;
    if (i < OUTCH * KIM) {
        float4 v = *(const float4*)(wf + i);
        short4v s;
        s[0] = (short)f2bf(v.x); s[1] = (short)f2bf(v.y);
        s[2] = (short)f2bf(v.z); s[3] = (short)f2bf(v.w);
        *(short4v*)(wfb + i) = s;
    }
}
// x [64][256][196] f32 -> Xt [64][196][256] bf16 (LDS transpose)
__global__ __launch_bounds__(256) void k_xt(const float* __restrict__ x,
                                            unsigned short* __restrict__ Xt) {
    __shared__ float xs[32][197];
    int b = blockIdx.y, c0 = blockIdx.x * 32, tid = threadIdx.x;
    for (int i = tid; i < 32 * P; i += 256) {
        int ci = i / P, pp = i - ci * P;
        xs[ci][pp] = x[((size_t)b * DIMC + c0 + ci) * P + pp];
    }
    __syncthreads();
    for (int j = tid; j < P * 32; j += 256) {
        int ci = j & 31, pp = j >> 5;
        Xt[((size_t)b * P + pp) * DIMC + c0 + ci] = f2bf(xs[ci][pp]);
    }
}

// ---------------- weight-generator net head ----------------
__device__ __forceinline__ void block_reduce2(float& s, float& ss, float* red, int tid, int nthreads) {
    #pragma unroll
    for (int off = 32; off > 0; off >>= 1) {
        s  += __shfl_down(s, off);
        ss += __shfl_down(ss, off);
    }
    int wid = tid >> 6, nw = nthreads >> 6;
    if ((tid & 63) == 0) { red[wid*2] = s; red[wid*2+1] = ss; }
    __syncthreads();
    if (tid == 0) {
        float S = 0.f, SS = 0.f;
        for (int i = 0; i < nw; i++) { S += red[i*2]; SS += red[i*2+1]; }
        red[0] = S; red[1] = SS;
    }
    __syncthreads();
    s = red[0]; ss = red[1];
}

__global__ __launch_bounds__(256) void k_stage0(const float* __restrict__ posi,
                                                const float* __restrict__ w0,
                                                const float* __restrict__ g0,
                                                const float* __restrict__ b0,
                                                float* __restrict__ a_out) {
    __shared__ __align__(16) float ppad[POSI][16][16];
    __shared__ __align__(16) float t[INTER * P];
    __shared__ float red[64];
    int tid = threadIdx.x;
    for (int i = tid; i < POSI * 256; i += 256) {
        int c = i >> 8, r = i & 255, ly = r >> 4, lx = r & 15;
        float v = 0.f;
        if (ly >= 1 && ly <= HP && lx >= 1 && lx <= WP) v = posi[c*P + (ly-1)*WP + (lx-1)];
        ppad[c][ly][lx] = v;
    }
    __syncthreads();
    float s = 0.f, ss = 0.f;
    for (int idx = tid; idx < INTER * P; idx += 256) {
        int c = idx / P, p = idx - c*P, y = p / WP, x = p - (p/WP)*WP;
        float acc = 0.f;
        #pragma unroll
        for (int ci = 0; ci < POSI; ci++)
            #pragma unroll
            for (int dy = 0; dy < 3; dy++)
                #pragma unroll
                for (int dx = 0; dx < 3; dx++)
                    acc += w0[((c*POSI + ci)*3 + dy)*3 + dx] * ppad[ci][y+dy][x+dx];
        t[idx] = acc; s += acc; ss += acc*acc;
    }
    block_reduce2(s, ss, red, tid, 256);
    float mu = s / (float)(INTER*P);
    float var = ss / (float)(INTER*P) - mu*mu;
    float rstd = rsqrtf(var + EPSLN);
    for (int idx = tid; idx < INTER * P; idx += 256) {
        float v = (t[idx] - mu) * rstd * g0[idx] + b0[idx];
        a_out[idx] = v > 0.f ? v : 0.f;
    }
}

__global__ __launch_bounds__(256) void k_conv64(const float* __restrict__ a,
                                                const float* __restrict__ w,
                                                float* __restrict__ v) {
    __shared__ __align__(16) float as[INTER][16][16];
    int tid = threadIdx.x;
    for (int i = tid; i < INTER * 256; i += 256) {
        int c = i >> 8, r = i & 255, ly = r >> 4, lx = r & 15;
        float val = 0.f;
        if (ly >= 1 && ly <= HP && lx >= 1 && lx <= WP) val = a[c*P + (ly-1)*WP + (lx-1)];
        as[c][ly][lx] = val;
    }
    __syncthreads();
    int idx = blockIdx.x * 256 + tid;
    int c = idx / P, p = idx - c*P, y = p / WP, x = p - (p/WP)*WP;
    float acc = 0.f;
    for (int ci = 0; ci < INTER; ci++) {
        const float* wr = w + (c*INTER + ci)*9;
        acc += wr[0]*as[ci][y  ][x] + wr[1]*as[ci][y  ][x+1] + wr[2]*as[ci][y  ][x+2]
             + wr[3]*as[ci][y+1][x] + wr[4]*as[ci][y+1][x+1] + wr[5]*as[ci][y+1][x+2]
             + wr[6]*as[ci][y+2][x] + wr[7]*as[ci][y+2][x+1] + wr[8]*as[ci][y+2][x+2];
    }
    v[idx] = acc;
}

__global__ __launch_bounds__(1024) void k_lnrelu(const float* __restrict__ v,
                                                 const float* __restrict__ g,
                                                 const float* __restrict__ b,
                                                 float* __restrict__ a) {
    __shared__ float red[64];
    int tid = threadIdx.x;
    float s = 0.f, ss = 0.f;
    float vals[13];
    int cnt = 0;
    for (int idx = tid; idx < INTER * P; idx += 1024) {
        float x = v[idx]; vals[cnt++] = x; s += x; ss += x*x;
    }
    block_reduce2(s, ss, red, tid, 1024);
    float mu = s / (float)(INTER*P);
    float var = ss / (float)(INTER*P) - mu*mu;
    float rstd = rsqrtf(var + EPSLN);
    cnt = 0;
    for (int idx = tid; idx < INTER * P; idx += 1024) {
        float x = (vals[cnt++] - mu) * rstd * g[idx] + b[idx];
        a[idx] = x > 0.f ? x : 0.f;
    }
}

// im2col of final activation: imc[p][ci*9+k] bf16
__global__ void k_im2col(const float* __restrict__ a, unsigned short* __restrict__ imc) {
    int idx = blockIdx.x * 256 + threadIdx.x;
    if (idx >= P * KIM) return;
    int p = idx / KIM, q = idx - p * KIM;
    int ci = q / 9, k = q - ci * 9;
    int y = p / WP + k / 3 - 1, x = p % WP + k % 3 - 1;
    float v = 0.f;
    if (y >= 0 && y < HP && x >= 0 && x < WP) v = a[ci * P + y * WP + x];
    imc[idx] = f2bf(v);
}

// final conv as MFMA GEMM: wgt[oc][p] = sum_q wfb[oc][q] imc[p][q]
// 765 blocks x 1 wave; wave = 16 oc rows x 196 p (13 frags) x 18 k-steps
__global__ __launch_bounds__(64) void k_gemm_wf(const unsigned short* __restrict__ wfb,
                                                const unsigned short* __restrict__ imc,
                                                unsigned short* __restrict__ wgtT) {
    int l = threadIdx.x;
    int quad = l >> 4, c16 = l & 15;
    int o0 = blockIdx.x * 16;                 // 765 * 16 = 12240 exactly
    f32x4 acc[13];
    #pragma unroll
    for (int f = 0; f < 13; f++) acc[f] = (f32x4)0.f;
    const unsigned short* Arow = wfb + (size_t)(o0 + c16) * KIM + quad * 8;
    const unsigned short* Bb   = imc + quad * 8;
    for (int kk = 0; kk < 18; kk++) {
        int k0 = kk * 32;
        short8 af = *(const short8*)(Arow + k0);
        #pragma unroll
        for (int f = 0; f < 13; f++) {
            int p = f * 16 + c16;
            short8 bf = (short8)0;
            if (p < P) bf = *(const short8*)(Bb + (size_t)p * KIM + k0);
            acc[f] = __builtin_amdgcn_mfma_f32_16x16x32_bf16(af, bf, acc[f], 0, 0, 0);
        }
    }
    #pragma unroll
    for (int f = 0; f < 13; f++) {
        int p = f * 16 + c16;
        if (p < P) {
            #pragma unroll
            for (int r = 0; r < 4; r++) {
                int oc = o0 + quad * 4 + r;
                int ch = oc / 9, k = oc - ch * 9;
                wgtT[((size_t)p * 9 + k) * CHN + ch] = f2bf(acc[f][r]);
            }
        }
    }
}

// ---------------- MFMA GEMM 1: h1t[b][p][o] = sum_c W_in[o][c] x[b][c][p] ----------------
__global__ __launch_bounds__(256) void k_gemm_in(const unsigned short* __restrict__ Wb,
                                                 const unsigned short* __restrict__ Xt,
                                                 unsigned short* __restrict__ h1t) {
    int tid = threadIdx.x;
    int w = tid >> 6, l = tid & 63;
    int quad = l >> 4, c16 = l & 15;
    int b = blockIdx.y;
    int o0 = blockIdx.x * 64 + w * 16;
    if (o0 >= CHN) return;
    f32x4 acc[13];
    #pragma unroll
    for (int f = 0; f < 13; f++) acc[f] = (f32x4)0.f;
    const unsigned short* Arow = Wb + (size_t)(o0 + c16) * DIMC + quad * 8;
    const unsigned short* Xb   = Xt + (size_t)b * P * DIMC + quad * 8;
    #pragma unroll
    for (int kk = 0; kk < 8; kk++) {
        int k0 = kk * 32;
        short8 af = *(const short8*)(Arow + k0);
        #pragma unroll
        for (int f = 0; f < 13; f++) {
            int p = f * 16 + c16;
            short8 bf = (short8)0;
            if (p < P) bf = *(const short8*)(Xb + (size_t)p * DIMC + k0);
            acc[f] = __builtin_amdgcn_mfma_f32_16x16x32_bf16(af, bf, acc[f], 0, 0, 0);
        }
    }
    #pragma unroll
    for (int f = 0; f < 13; f++) {
        int p = f * 16 + c16;
        if (p < P) {
            short4v sv;
            sv[0] = (short)f2bf(acc[f][0]);
            sv[1] = (short)f2bf(acc[f][1]);
            sv[2] = (short)f2bf(acc[f][2]);
            sv[3] = (short)f2bf(acc[f][3]);
            *(short4v*)(h1t + ((size_t)b * P + p) * CHN + o0 + quad * 4) = sv;
        }
    }
}

// ---------------- fused tvconv + gelu-gate ----------------
__global__ __launch_bounds__(256) void k_tvg(const unsigned short* __restrict__ h1t,
                                             const unsigned short* __restrict__ wgtT,
                                             unsigned short* __restrict__ hgt) {
    int p = blockIdx.x, b = blockIdx.y, tid = threadIdx.x;
    int y = p / WP, x = p - (p / WP) * WP;
    int pn[9]; bool pv[9];
    #pragma unroll
    for (int k = 0; k < 9; k++) {
        int yy = y + k / 3 - 1, xx = x + (k % 3) - 1;
        pv[k] = (yy >= 0 && yy < HP && xx >= 0 && xx < WP);
        pn[k] = pv[k] ? yy * WP + xx : 0;
    }
    const unsigned short* wrow = wgtT + (size_t)p * 9 * CHN;
    const unsigned short* hb   = h1t + (size_t)b * P * CHN;
    unsigned short* orow = hgt + ((size_t)b * P + p) * KPAD;
    for (int c = tid; c < HID; c += 256) {
        float s1 = 0.f, s2 = 0.f;
        #pragma unroll
        for (int k = 0; k < 9; k++) {
            if (!pv[k]) continue;
            const unsigned short* hr = hb + (size_t)pn[k] * CHN;
            s1 += bf2f(wrow[k * CHN + c])       * bf2f(hr[c]);
            s2 += bf2f(wrow[k * CHN + HID + c]) * bf2f(hr[HID + c]);
        }
        float gl = 0.5f * s1 * (1.f + erff(s1 * 0.70710678118654752f));
        orow[c] = f2bf(gl * s2);
    }
    if (tid < KPAD - HID) orow[HID + tid] = 0;
}

// ---------------- MFMA GEMM 2: out[b][o][p] = sum_c W_out[o][c] hg[b][c][p] ----------------
__global__ __launch_bounds__(256) void k_gemm_out(const unsigned short* __restrict__ Wb,
                                                  const unsigned short* __restrict__ hgt,
                                                  float* __restrict__ out) {
    int tid = threadIdx.x;
    int w = tid >> 6, l = tid & 63;
    int quad = l >> 4, c16 = l & 15;
    int b = blockIdx.y;
    int o0 = blockIdx.x * 64 + w * 16;
    f32x4 acc[13];
    #pragma unroll
    for (int f = 0; f < 13; f++) acc[f] = (f32x4)0.f;
    const unsigned short* Arow = Wb + (size_t)(o0 + c16) * KPAD + quad * 8;
    const unsigned short* Hb   = hgt + (size_t)b * P * KPAD + quad * 8;
    for (int kk = 0; kk < 22; kk++) {
        int k0 = kk * 32;
        short8 af = *(const short8*)(Arow + k0);
        #pragma unroll
        for (int f = 0; f < 13; f++) {
            int p = f * 16 + c16;
            short8 bf = (short8)0;
            if (p < P) bf = *(const short8*)(Hb + (size_t)p * KPAD + k0);
            acc[f] = __builtin_amdgcn_mfma_f32_16x16x32_bf16(af, bf, acc[f], 0, 0, 0);
        }
    }
    #pragma unroll
    for (int f = 0; f < 13; f++) {
        int p = f * 16 + c16;
        if (p < P) {
            #pragma unroll
            for (int r = 0; r < 4; r++) {
                int o = o0 + quad * 4 + r;
                out[((size_t)b * DIMC + o) * P + p] = acc[f][r];
            }
        }
    }
}

extern "C" void kernel_launch(void* const* d_in, const int* in_sizes, int n_in,
                              void* d_out, int out_size, void* d_ws, size_t ws_size,
                              hipStream_t stream) {
    (void)in_sizes; (void)n_in; (void)out_size; (void)ws_size;
    const float* x     = (const float*)d_in[0];
    const float* W_in  = (const float*)d_in[1];
    const float* posi  = (const float*)d_in[2];
    const float* w0    = (const float*)d_in[3];
    const float* g0    = (const float*)d_in[4];
    const float* b0    = (const float*)d_in[5];
    const float* w1    = (const float*)d_in[6];
    const float* g1    = (const float*)d_in[7];
    const float* b1    = (const float*)d_in[8];
    const float* w2    = (const float*)d_in[9];
    const float* g2    = (const float*)d_in[10];
    const float* b2    = (const float*)d_in[11];
    const float* wf    = (const float*)d_in[12];
    const float* W_out = (const float*)d_in[13];
    float* out = (float*)d_out;
    char* ws = (char*)d_ws;

    unsigned short* Wbin  = (unsigned short*)(ws + OFS_WBIN);
    unsigned short* Wbout = (unsigned short*)(ws + OFS_WBOUT);
    unsigned short* Xt    = (unsigned short*)(ws + OFS_XT);
    float*          a_buf = (float*)(ws + OFS_ABUF);
    float*          v_buf = (float*)(ws + OFS_VBUF);
    unsigned short* wgtT  = (unsigned short*)(ws + OFS_WGTT);
    unsigned short* h1t   = (unsigned short*)(ws + OFS_H1T);
    unsigned short* hgt   = (unsigned short*)(ws + OFS_HGT);
    unsigned short* wfb   = (unsigned short*)(ws + OFS_WFB);
    unsigned short* imc   = (unsigned short*)(ws + OFS_IMC);

    // casts / transposes
    k_cast_win <<<(CHN*DIMC + 255)/256, 256, 0, stream>>>(W_in, Wbin);
    k_cast_wout<<<(DIMC*KPAD + 255)/256, 256, 0, stream>>>(W_out, Wbout);
    k_cast_wf  <<<(OUTCH*KIM/4 + 255)/256, 256, 0, stream>>>(wf, wfb);
    k_xt       <<<dim3(DIMC/32, BATCH), 256, 0, stream>>>(x, Xt);

    // weight-generator network
    k_stage0<<<1, 256, 0, stream>>>(posi, w0, g0, b0, a_buf);
    k_conv64<<<49, 256, 0, stream>>>(a_buf, w1, v_buf);
    k_lnrelu<<<1, 1024, 0, stream>>>(v_buf, g1, b1, a_buf);
    k_conv64<<<49, 256, 0, stream>>>(a_buf, w2, v_buf);
    k_lnrelu<<<1, 1024, 0, stream>>>(v_buf, g2, b2, a_buf);
    k_im2col<<<(P*KIM + 255)/256, 256, 0, stream>>>(a_buf, imc);
    k_gemm_wf<<<OUTCH/16, 64, 0, stream>>>(wfb, imc, wgtT);

    // main path (MFMA)
    k_gemm_in <<<dim3(22, BATCH), 256, 0, stream>>>(Wbin, Xt, h1t);
    k_tvg     <<<dim3(P, BATCH), 256, 0, stream>>>(h1t, wgtT, hgt);
    k_gemm_out<<<dim3(4, BATCH), 256, 0, stream>>>(Wbout, hgt, out);
}

// Round 4
// 375.481 us; speedup vs baseline: 2.6340x; 1.2244x over previous
//
#include <hip/hip_runtime.h>
#include <math.h>

// ---- problem constants ----
#define DIMC   256
#define HID    680
#define CHN    1360
#define HP     14
#define WP     14
#define P      196
#define POSI   4
#define INTER  64
#define BATCH  64
#define KPAD   704          // 680 padded to 22*32
#define OUTCH  12240        // CHN*9
#define KIM    576          // INTER*9
#define MPADIN 1408         // 1360 padded to 11*128
#define EPSLN  1e-5f

typedef __attribute__((ext_vector_type(8))) short short8;
typedef __attribute__((ext_vector_type(4))) short short4v;
typedef __attribute__((ext_vector_type(4))) float f32x4;

// ---- workspace layout (bytes) ----
#define OFS_WBIN  0u                  // 1408*256*2   = 720896
#define OFS_WBOUT 720896u             // 256*704*2    = 360448
#define OFS_XT    1081344u            // 64*196*256*2 = 6422528
#define OFS_ABUF  7503872u            // 12544*4
#define OFS_VBUF  7554048u            // 12544*4
#define OFS_WGTT  7604224u            // 196*9*1360*2 = 4798080
#define OFS_H1T   12402304u           // 64*196*1360*2 = 34127872
#define OFS_HGT   46530176u           // 64*196*704*2  = 17661952
#define OFS_WFB   64192128u           // 12240*576*2   = 14100480
#define OFS_IMC   78292608u           // 196*576*2     = 225792  (end 78.5MB)

__device__ __forceinline__ unsigned short f2bf(float f) {
    union { float f; unsigned u; } v; v.f = f;
    unsigned u = v.u;
    return (unsigned short)((u + 0x7FFFu + ((u >> 16) & 1u)) >> 16);   // RNE
}
__device__ __forceinline__ float bf2f(unsigned short h) {
    union { unsigned u; float f; } v; v.u = ((unsigned)h) << 16; return v.f;
}

// async 16B global->LDS (wave-uniform LDS base + lane*16)
__device__ __forceinline__ void gl2lds16(const unsigned short* g, unsigned short* l) {
    __builtin_amdgcn_global_load_lds(
        (const __attribute__((address_space(1))) unsigned int*)g,
        (__attribute__((address_space(3))) unsigned int*)l, 16, 0, 0);
}
// swizzled fragment read: row-major LDS tile, row stride 32 bf16, slot-rotated 16B pieces
__device__ __forceinline__ short8 fragld(const unsigned short* S, int row, int quad) {
    int slot = ((row >> 1) + quad) & 3;
    return *(const short8*)(S + row * 32 + slot * 8);
}

// ---------------- small casts ----------------
__global__ void k_cast_win(const float* __restrict__ W, unsigned short* __restrict__ Wb) {
    int i = blockIdx.x * 256 + threadIdx.x;
    if (i < MPADIN * DIMC) Wb[i] = (i < CHN * DIMC) ? f2bf(W[i]) : (unsigned short)0;
}
__global__ void k_cast_wout(const float* __restrict__ W, unsigned short* __restrict__ Wb) {
    int i = blockIdx.x * 256 + threadIdx.x;
    if (i < DIMC * KPAD) {
        int o = i / KPAD, k = i - o * KPAD;
        Wb[i] = f2bf(k < HID ? W[o * HID + k] : 0.f);
    }
}
__global__ void k_cast_wf(const float* __restrict__ wf, unsigned short* __restrict__ wfb) {
    int i = (blockIdx.x * 256 + threadIdx.x) * 4;
    if (i < OUTCH * KIM) {
        float4 v = *(const float4*)(wf + i);
        short4v s;
        s[0] = (short)f2bf(v.x); s[1] = (short)f2bf(v.y);
        s[2] = (short)f2bf(v.z); s[3] = (short)f2bf(v.w);
        *(short4v*)(wfb + i) = s;
    }
}
// x [64][256][196] f32 -> Xt [64][196][256] bf16
__global__ __launch_bounds__(256) void k_xt(const float* __restrict__ x,
                                            unsigned short* __restrict__ Xt) {
    __shared__ float xs[32][197];
    int b = blockIdx.y, c0 = blockIdx.x * 32, tid = threadIdx.x;
    for (int i = tid; i < 32 * P; i += 256) {
        int ci = i / P, pp = i - ci * P;
        xs[ci][pp] = x[((size_t)b * DIMC + c0 + ci) * P + pp];
    }
    __syncthreads();
    for (int j = tid; j < P * 32; j += 256) {
        int ci = j & 31, pp = j >> 5;
        Xt[((size_t)b * P + pp) * DIMC + c0 + ci] = f2bf(xs[ci][pp]);
    }
}

// ---------------- weight-generator net head (unchanged) ----------------
__device__ __forceinline__ void block_reduce2(float& s, float& ss, float* red, int tid, int nthreads) {
    #pragma unroll
    for (int off = 32; off > 0; off >>= 1) {
        s  += __shfl_down(s, off);
        ss += __shfl_down(ss, off);
    }
    int wid = tid >> 6, nw = nthreads >> 6;
    if ((tid & 63) == 0) { red[wid*2] = s; red[wid*2+1] = ss; }
    __syncthreads();
    if (tid == 0) {
        float S = 0.f, SS = 0.f;
        for (int i = 0; i < nw; i++) { S += red[i*2]; SS += red[i*2+1]; }
        red[0] = S; red[1] = SS;
    }
    __syncthreads();
    s = red[0]; ss = red[1];
}

__global__ __launch_bounds__(256) void k_stage0(const float* __restrict__ posi,
                                                const float* __restrict__ w0,
                                                const float* __restrict__ g0,
                                                const float* __restrict__ b0,
                                                float* __restrict__ a_out) {
    __shared__ __align__(16) float ppad[POSI][16][16];
    __shared__ __align__(16) float t[INTER * P];
    __shared__ float red[64];
    int tid = threadIdx.x;
    for (int i = tid; i < POSI * 256; i += 256) {
        int c = i >> 8, r = i & 255, ly = r >> 4, lx = r & 15;
        float v = 0.f;
        if (ly >= 1 && ly <= HP && lx >= 1 && lx <= WP) v = posi[c*P + (ly-1)*WP + (lx-1)];
        ppad[c][ly][lx] = v;
    }
    __syncthreads();
    float s = 0.f, ss = 0.f;
    for (int idx = tid; idx < INTER * P; idx += 256) {
        int c = idx / P, p = idx - c*P, y = p / WP, x = p - (p/WP)*WP;
        float acc = 0.f;
        #pragma unroll
        for (int ci = 0; ci < POSI; ci++)
            #pragma unroll
            for (int dy = 0; dy < 3; dy++)
                #pragma unroll
                for (int dx = 0; dx < 3; dx++)
                    acc += w0[((c*POSI + ci)*3 + dy)*3 + dx] * ppad[ci][y+dy][x+dx];
        t[idx] = acc; s += acc; ss += acc*acc;
    }
    block_reduce2(s, ss, red, tid, 256);
    float mu = s / (float)(INTER*P);
    float var = ss / (float)(INTER*P) - mu*mu;
    float rstd = rsqrtf(var + EPSLN);
    for (int idx = tid; idx < INTER * P; idx += 256) {
        float v = (t[idx] - mu) * rstd * g0[idx] + b0[idx];
        a_out[idx] = v > 0.f ? v : 0.f;
    }
}

__global__ __launch_bounds__(256) void k_conv64(const float* __restrict__ a,
                                                const float* __restrict__ w,
                                                float* __restrict__ v) {
    __shared__ __align__(16) float as[INTER][16][16];
    int tid = threadIdx.x;
    for (int i = tid; i < INTER * 256; i += 256) {
        int c = i >> 8, r = i & 255, ly = r >> 4, lx = r & 15;
        float val = 0.f;
        if (ly >= 1 && ly <= HP && lx >= 1 && lx <= WP) val = a[c*P + (ly-1)*WP + (lx-1)];
        as[c][ly][lx] = val;
    }
    __syncthreads();
    int idx = blockIdx.x * 256 + tid;
    int c = idx / P, p = idx - c*P, y = p / WP, x = p - (p/WP)*WP;
    float acc = 0.f;
    for (int ci = 0; ci < INTER; ci++) {
        const float* wr = w + (c*INTER + ci)*9;
        acc += wr[0]*as[ci][y  ][x] + wr[1]*as[ci][y  ][x+1] + wr[2]*as[ci][y  ][x+2]
             + wr[3]*as[ci][y+1][x] + wr[4]*as[ci][y+1][x+1] + wr[5]*as[ci][y+1][x+2]
             + wr[6]*as[ci][y+2][x] + wr[7]*as[ci][y+2][x+1] + wr[8]*as[ci][y+2][x+2];
    }
    v[idx] = acc;
}

__global__ __launch_bounds__(1024) void k_lnrelu(const float* __restrict__ v,
                                                 const float* __restrict__ g,
                                                 const float* __restrict__ b,
                                                 float* __restrict__ a) {
    __shared__ float red[64];
    int tid = threadIdx.x;
    float s = 0.f, ss = 0.f;
    float vals[13];
    int cnt = 0;
    for (int idx = tid; idx < INTER * P; idx += 1024) {
        float x = v[idx]; vals[cnt++] = x; s += x; ss += x*x;
    }
    block_reduce2(s, ss, red, tid, 1024);
    float mu = s / (float)(INTER*P);
    float var = ss / (float)(INTER*P) - mu*mu;
    float rstd = rsqrtf(var + EPSLN);
    cnt = 0;
    for (int idx = tid; idx < INTER * P; idx += 1024) {
        float x = (vals[cnt++] - mu) * rstd * g[idx] + b[idx];
        a[idx] = x > 0.f ? x : 0.f;
    }
}

__global__ void k_im2col(const float* __restrict__ a, unsigned short* __restrict__ imc) {
    int idx = blockIdx.x * 256 + threadIdx.x;
    if (idx >= P * KIM) return;
    int p = idx / KIM, q = idx - p * KIM;
    int ci = q / 9, k = q - ci * 9;
    int y = p / WP + k / 3 - 1, x = p % WP + k % 3 - 1;
    float v = 0.f;
    if (y >= 0 && y < HP && x >= 0 && x < WP) v = a[ci * P + y * WP + x];
    imc[idx] = f2bf(v);
}

// final conv as MFMA GEMM (direct-from-global; small enough)
__global__ __launch_bounds__(64) void k_gemm_wf(const unsigned short* __restrict__ wfb,
                                                const unsigned short* __restrict__ imc,
                                                unsigned short* __restrict__ wgtT) {
    int l = threadIdx.x;
    int quad = l >> 4, c16 = l & 15;
    int o0 = blockIdx.x * 16;
    f32x4 acc[13];
    #pragma unroll
    for (int f = 0; f < 13; f++) acc[f] = (f32x4)0.f;
    const unsigned short* Arow = wfb + (size_t)(o0 + c16) * KIM + quad * 8;
    const unsigned short* Bb   = imc + quad * 8;
    for (int kk = 0; kk < 18; kk++) {
        int k0 = kk * 32;
        short8 af = *(const short8*)(Arow + k0);
        #pragma unroll
        for (int f = 0; f < 13; f++) {
            int p = f * 16 + c16;
            short8 bf = (short8)0;
            if (p < P) bf = *(const short8*)(Bb + (size_t)p * KIM + k0);
            acc[f] = __builtin_amdgcn_mfma_f32_16x16x32_bf16(af, bf, acc[f], 0, 0, 0);
        }
    }
    #pragma unroll
    for (int f = 0; f < 13; f++) {
        int p = f * 16 + c16;
        if (p < P) {
            #pragma unroll
            for (int r = 0; r < 4; r++) {
                int oc = o0 + quad * 4 + r;
                int ch = oc / 9, k = oc - ch * 9;
                wgtT[((size_t)p * 9 + k) * CHN + ch] = f2bf(acc[f][r]);
            }
        }
    }
}

// ---------------- tiled MFMA GEMM 1: h1t[n][m] = sum_k Wbin[m][k] Xt[n][k] ----------------
// block 128m x 128n, 4 waves each 64x64, K=256 in 8 chunks of 32, LDS staged via global_load_lds
__global__ __launch_bounds__(256) void k_gemm_in(const unsigned short* __restrict__ A,
                                                 const unsigned short* __restrict__ B,
                                                 unsigned short* __restrict__ C) {
    __shared__ __align__(16) unsigned short As[128 * 32];
    __shared__ __align__(16) unsigned short Bs[128 * 32];
    int tid = threadIdx.x;
    int w = tid >> 6, lane = tid & 63, quad = lane >> 4, c16 = lane & 15;
    int m0 = blockIdx.x * 128, n0 = blockIdx.y * 128;
    int wm = (w & 1) * 64, wn = (w >> 1) * 64;
    f32x4 acc[4][4];
    #pragma unroll
    for (int i = 0; i < 4; i++)
        #pragma unroll
        for (int j = 0; j < 4; j++) acc[i][j] = (f32x4)0.f;

    for (int kc = 0; kc < 8; ++kc) {
        int k0 = kc * 32;
        if (kc) __syncthreads();
        #pragma unroll
        for (int i = tid; i < 512; i += 256) {          // A: 128 rows x 4 pieces
            int r = i >> 2, s = i & 3, q = (s - (r >> 1)) & 3;
            gl2lds16(A + (size_t)(m0 + r) * DIMC + k0 + q * 8, As + (i & ~63) * 8);
        }
        #pragma unroll
        for (int i = tid; i < 512; i += 256) {          // B: 128 rows x 4 pieces
            int r = i >> 2, s = i & 3, q = (s - (r >> 1)) & 3;
            gl2lds16(B + (size_t)(n0 + r) * DIMC + k0 + q * 8, Bs + (i & ~63) * 8);
        }
        __syncthreads();
        short8 af[4], bfr[4];
        #pragma unroll
        for (int i = 0; i < 4; i++) af[i] = fragld(As, wm + i * 16 + c16, quad);
        #pragma unroll
        for (int j = 0; j < 4; j++) bfr[j] = fragld(Bs, wn + j * 16 + c16, quad);
        #pragma unroll
        for (int i = 0; i < 4; i++)
            #pragma unroll
            for (int j = 0; j < 4; j++)
                acc[i][j] = __builtin_amdgcn_mfma_f32_16x16x32_bf16(af[i], bfr[j], acc[i][j], 0, 0, 0);
    }
    #pragma unroll
    for (int j = 0; j < 4; j++) {
        int n = n0 + wn + j * 16 + c16;
        unsigned short* dst = C + (size_t)n * CHN;
        #pragma unroll
        for (int i = 0; i < 4; i++) {
            int m = m0 + wm + i * 16 + quad * 4;
            if (m < CHN) {
                short4v sv;
                sv[0] = (short)f2bf(acc[i][j][0]);
                sv[1] = (short)f2bf(acc[i][j][1]);
                sv[2] = (short)f2bf(acc[i][j][2]);
                sv[3] = (short)f2bf(acc[i][j][3]);
                *(short4v*)(dst + m) = sv;
            }
        }
    }
}

// ---------------- fused tvconv + gelu-gate: block=(p, 16 b's), wgt row in LDS ----------------
__global__ __launch_bounds__(256) void k_tvg(const unsigned short* __restrict__ h1t,
                                             const unsigned short* __restrict__ wgtT,
                                             unsigned short* __restrict__ hgt) {
    __shared__ __align__(16) unsigned short wl[9 * CHN];   // 24480 B
    int p = blockIdx.x, b0 = blockIdx.y * 16, tid = threadIdx.x;
    const unsigned short* wrow = wgtT + (size_t)p * 9 * CHN;
    for (int i = tid * 8; i < 9 * CHN; i += 256 * 8)
        *(short8*)(wl + i) = *(const short8*)(wrow + i);
    int y = p / WP, x = p - (p / WP) * WP;
    int pn[9]; bool pv[9];
    #pragma unroll
    for (int k = 0; k < 9; k++) {
        int yy = y + k / 3 - 1, xx = x + (k % 3) - 1;
        pv[k] = (yy >= 0 && yy < HP && xx >= 0 && xx < WP);
        pn[k] = pv[k] ? yy * WP + xx : 0;
    }
    __syncthreads();
    for (int j = tid; j < 16 * 85; j += 256) {
        int bl = j / 85, c = (j - bl * 85) * 8;
        int b = b0 + bl;
        const unsigned short* hb = h1t + (size_t)b * P * CHN;
        float s1[8], s2[8];
        #pragma unroll
        for (int e = 0; e < 8; e++) { s1[e] = 0.f; s2[e] = 0.f; }
        #pragma unroll
        for (int k = 0; k < 9; k++) {
            if (!pv[k]) continue;                        // block-uniform
            const unsigned short* hr = hb + (size_t)pn[k] * CHN + c;
            short8 h1v = *(const short8*)hr;
            short8 h2v = *(const short8*)(hr + HID);
            short8 w1v = *(const short8*)(wl + k * CHN + c);
            short8 w2v = *(const short8*)(wl + k * CHN + HID + c);
            #pragma unroll
            for (int e = 0; e < 8; e++) {
                s1[e] += bf2f((unsigned short)w1v[e]) * bf2f((unsigned short)h1v[e]);
                s2[e] += bf2f((unsigned short)w2v[e]) * bf2f((unsigned short)h2v[e]);
            }
        }
        short8 o;
        #pragma unroll
        for (int e = 0; e < 8; e++) {
            float gl = 0.5f * s1[e] * (1.f + erff(s1[e] * 0.70710678118654752f));
            o[e] = (short)f2bf(gl * s2[e]);
        }
        *(short8*)(hgt + ((size_t)b * P + p) * KPAD + c) = o;
    }
    if (tid < 48) {                                      // zero k-pad cols 680..703
        int bl = tid / 3, z = (tid - bl * 3) * 8;
        *(short8*)(hgt + ((size_t)(b0 + bl) * P + p) * KPAD + HID + z) = (short8)0;
    }
}

// ---------------- tiled MFMA GEMM 2: out[m][n] = sum_k Wbout[m][k] hgt[n][k] ----------------
// block 64m x 128n, 4 waves each 32x64, K=704 in 22 chunks
__global__ __launch_bounds__(256) void k_gemm_out(const unsigned short* __restrict__ A,
                                                  const unsigned short* __restrict__ B,
                                                  float* __restrict__ out) {
    __shared__ __align__(16) unsigned short As[64 * 32];
    __shared__ __align__(16) unsigned short Bs[128 * 32];
    int tid = threadIdx.x;
    int w = tid >> 6, lane = tid & 63, quad = lane >> 4, c16 = lane & 15;
    int m0 = blockIdx.x * 64, n0 = blockIdx.y * 128;
    int wm = (w & 1) * 32, wn = (w >> 1) * 64;
    f32x4 acc[2][4];
    #pragma unroll
    for (int i = 0; i < 2; i++)
        #pragma unroll
        for (int j = 0; j < 4; j++) acc[i][j] = (f32x4)0.f;

    for (int kc = 0; kc < 22; ++kc) {
        int k0 = kc * 32;
        if (kc) __syncthreads();
        {                                                // A: 64 rows x 4 = 256 pieces
            int i = tid;
            int r = i >> 2, s = i & 3, q = (s - (r >> 1)) & 3;
            gl2lds16(A + (size_t)(m0 + r) * KPAD + k0 + q * 8, As + (i & ~63) * 8);
        }
        #pragma unroll
        for (int i = tid; i < 512; i += 256) {           // B: 128 rows x 4 pieces
            int r = i >> 2, s = i & 3, q = (s - (r >> 1)) & 3;
            gl2lds16(B + (size_t)(n0 + r) * KPAD + k0 + q * 8, Bs + (i & ~63) * 8);
        }
        __syncthreads();
        short8 af[2], bfr[4];
        #pragma unroll
        for (int i = 0; i < 2; i++) af[i] = fragld(As, wm + i * 16 + c16, quad);
        #pragma unroll
        for (int j = 0; j < 4; j++) bfr[j] = fragld(Bs, wn + j * 16 + c16, quad);
        #pragma unroll
        for (int i = 0; i < 2; i++)
            #pragma unroll
            for (int j = 0; j < 4; j++)
                acc[i][j] = __builtin_amdgcn_mfma_f32_16x16x32_bf16(af[i], bfr[j], acc[i][j], 0, 0, 0);
    }
    #pragma unroll
    for (int j = 0; j < 4; j++) {
        int n = n0 + wn + j * 16 + c16;
        int b = n / P, pp = n - b * P;
        #pragma unroll
        for (int i = 0; i < 2; i++) {
            int m = m0 + wm + i * 16 + quad * 4;
            #pragma unroll
            for (int r = 0; r < 4; r++)
                out[((size_t)b * DIMC + m + r) * P + pp] = acc[i][j][r];
        }
    }
}

extern "C" void kernel_launch(void* const* d_in, const int* in_sizes, int n_in,
                              void* d_out, int out_size, void* d_ws, size_t ws_size,
                              hipStream_t stream) {
    (void)in_sizes; (void)n_in; (void)out_size; (void)ws_size;
    const float* x     = (const float*)d_in[0];
    const float* W_in  = (const float*)d_in[1];
    const float* posi  = (const float*)d_in[2];
    const float* w0    = (const float*)d_in[3];
    const float* g0    = (const float*)d_in[4];
    const float* b0    = (const float*)d_in[5];
    const float* w1    = (const float*)d_in[6];
    const float* g1    = (const float*)d_in[7];
    const float* b1    = (const float*)d_in[8];
    const float* w2    = (const float*)d_in[9];
    const float* g2    = (const float*)d_in[10];
    const float* b2    = (const float*)d_in[11];
    const float* wf    = (const float*)d_in[12];
    const float* W_out = (const float*)d_in[13];
    float* out = (float*)d_out;
    char* ws = (char*)d_ws;

    unsigned short* Wbin  = (unsigned short*)(ws + OFS_WBIN);
    unsigned short* Wbout = (unsigned short*)(ws + OFS_WBOUT);
    unsigned short* Xt    = (unsigned short*)(ws + OFS_XT);
    float*          a_buf = (float*)(ws + OFS_ABUF);
    float*          v_buf = (float*)(ws + OFS_VBUF);
    unsigned short* wgtT  = (unsigned short*)(ws + OFS_WGTT);
    unsigned short* h1t   = (unsigned short*)(ws + OFS_H1T);
    unsigned short* hgt   = (unsigned short*)(ws + OFS_HGT);
    unsigned short* wfb   = (unsigned short*)(ws + OFS_WFB);
    unsigned short* imc   = (unsigned short*)(ws + OFS_IMC);

    // casts / transposes
    k_cast_win <<<(MPADIN*DIMC + 255)/256, 256, 0, stream>>>(W_in, Wbin);
    k_cast_wout<<<(DIMC*KPAD + 255)/256, 256, 0, stream>>>(W_out, Wbout);
    k_cast_wf  <<<(OUTCH*KIM/4 + 255)/256, 256, 0, stream>>>(wf, wfb);
    k_xt       <<<dim3(DIMC/32, BATCH), 256, 0, stream>>>(x, Xt);

    // weight-generator network
    k_stage0<<<1, 256, 0, stream>>>(posi, w0, g0, b0, a_buf);
    k_conv64<<<49, 256, 0, stream>>>(a_buf, w1, v_buf);
    k_lnrelu<<<1, 1024, 0, stream>>>(v_buf, g1, b1, a_buf);
    k_conv64<<<49, 256, 0, stream>>>(a_buf, w2, v_buf);
    k_lnrelu<<<1, 1024, 0, stream>>>(v_buf, g2, b2, a_buf);
    k_im2col<<<(P*KIM + 255)/256, 256, 0, stream>>>(a_buf, imc);
    k_gemm_wf<<<OUTCH/16, 64, 0, stream>>>(wfb, imc, wgtT);

    // main path (tiled MFMA)
    k_gemm_in <<<dim3(MPADIN/128, (BATCH*P)/128), 256, 0, stream>>>(Wbin, Xt, h1t);
    k_tvg     <<<dim3(P, BATCH/16), 256, 0, stream>>>(h1t, wgtT, hgt);
    k_gemm_out<<<dim3(DIMC/64, (BATCH*P)/128), 256, 0, stream>>>(Wbout, hgt, out);
}

// Round 5
// 353.965 us; speedup vs baseline: 2.7941x; 1.0608x over previous
//
#include <hip/hip_runtime.h>
#include <math.h>

// ---- problem constants ----
#define DIMC   256
#define HID    680
#define CHN    1360
#define HP     14
#define WP     14
#define P      196
#define POSI   4
#define INTER  64
#define BATCH  64
#define KPAD   704          // 680 padded to 22*32
#define OUTCH  12240        // CHN*9
#define KIM    576          // INTER*9
#define MPADIN 1408         // 1360 padded to 11*128
#define EPSLN  1e-5f

typedef __attribute__((ext_vector_type(8))) short short8;
typedef __attribute__((ext_vector_type(4))) short short4v;
typedef __attribute__((ext_vector_type(4))) float f32x4;

// ---- workspace layout (bytes) ----
#define OFS_WBIN  0u                  // 1408*256*2   = 720896
#define OFS_WBOUT 720896u             // 256*704*2    = 360448
#define OFS_XT    1081344u            // 64*196*256*2 = 6422528
#define OFS_ABUF  7503872u            // 12544*4
#define OFS_VBUF  7554048u            // 12544*4
#define OFS_WGTT  7604224u            // 196*12240*2 = 4798080  (now [p][oc] layout)
#define OFS_H1T   12402304u           // 64*196*1360*2 = 34127872
#define OFS_HGT   46530176u           // 64*196*704*2  = 17661952
#define OFS_WFB   64192128u           // 12240*576*2   = 14100480
#define OFS_IMC   78292608u           // 196*576*2     = 225792  (end 78.5MB)

__device__ __forceinline__ unsigned short f2bf(float f) {
    union { float f; unsigned u; } v; v.f = f;
    unsigned u = v.u;
    return (unsigned short)((u + 0x7FFFu + ((u >> 16) & 1u)) >> 16);   // RNE
}
__device__ __forceinline__ float bf2f(unsigned short h) {
    union { unsigned u; float f; } v; v.u = ((unsigned)h) << 16; return v.f;
}

// async 16B global->LDS (wave-uniform LDS base + lane*16)
__device__ __forceinline__ void gl2lds16(const unsigned short* g, unsigned short* l) {
    __builtin_amdgcn_global_load_lds(
        (const __attribute__((address_space(1))) unsigned int*)g,
        (__attribute__((address_space(3))) unsigned int*)l, 16, 0, 0);
}
// swizzled fragment read: row-major LDS tile, row stride 32 bf16, slot-rotated 16B pieces
__device__ __forceinline__ short8 fragld(const unsigned short* S, int row, int quad) {
    int slot = ((row >> 1) + quad) & 3;
    return *(const short8*)(S + row * 32 + slot * 8);
}

// ---------------- small casts ----------------
__global__ void k_cast_win(const float* __restrict__ W, unsigned short* __restrict__ Wb) {
    int i = blockIdx.x * 256 + threadIdx.x;
    if (i < MPADIN * DIMC) Wb[i] = (i < CHN * DIMC) ? f2bf(W[i]) : (unsigned short)0;
}
__global__ void k_cast_wout(const float* __restrict__ W, unsigned short* __restrict__ Wb) {
    int i = blockIdx.x * 256 + threadIdx.x;
    if (i < DIMC * KPAD) {
        int o = i / KPAD, k = i - o * KPAD;
        Wb[i] = f2bf(k < HID ? W[o * HID + k] : 0.f);
    }
}
__global__ void k_cast_wf(const float* __restrict__ wf, unsigned short* __restrict__ wfb) {
    int i = (blockIdx.x * 256 + threadIdx.x) * 4;
    if (i < OUTCH * KIM) {
        float4 v = *(const float4*)(wf + i);
        short4v s;
        s[0] = (short)f2bf(v.x); s[1] = (short)f2bf(v.y);
        s[2] = (short)f2bf(v.z); s[3] = (short)f2bf(v.w);
        *(short4v*)(wfb + i) = s;
    }
}
// x [64][256][196] f32 -> Xt [64][196][256] bf16
__global__ __launch_bounds__(256) void k_xt(const float* __restrict__ x,
                                            unsigned short* __restrict__ Xt) {
    __shared__ float xs[32][197];
    int b = blockIdx.y, c0 = blockIdx.x * 32, tid = threadIdx.x;
    for (int i = tid; i < 32 * P; i += 256) {
        int ci = i / P, pp = i - ci * P;
        xs[ci][pp] = x[((size_t)b * DIMC + c0 + ci) * P + pp];
    }
    __syncthreads();
    for (int j = tid; j < P * 32; j += 256) {
        int ci = j & 31, pp = j >> 5;
        Xt[((size_t)b * P + pp) * DIMC + c0 + ci] = f2bf(xs[ci][pp]);
    }
}

// ---------------- weight-generator net head (unchanged) ----------------
__device__ __forceinline__ void block_reduce2(float& s, float& ss, float* red, int tid, int nthreads) {
    #pragma unroll
    for (int off = 32; off > 0; off >>= 1) {
        s  += __shfl_down(s, off);
        ss += __shfl_down(ss, off);
    }
    int wid = tid >> 6, nw = nthreads >> 6;
    if ((tid & 63) == 0) { red[wid*2] = s; red[wid*2+1] = ss; }
    __syncthreads();
    if (tid == 0) {
        float S = 0.f, SS = 0.f;
        for (int i = 0; i < nw; i++) { S += red[i*2]; SS += red[i*2+1]; }
        red[0] = S; red[1] = SS;
    }
    __syncthreads();
    s = red[0]; ss = red[1];
}

__global__ __launch_bounds__(256) void k_stage0(const float* __restrict__ posi,
                                                const float* __restrict__ w0,
                                                const float* __restrict__ g0,
                                                const float* __restrict__ b0,
                                                float* __restrict__ a_out) {
    __shared__ __align__(16) float ppad[POSI][16][16];
    __shared__ __align__(16) float t[INTER * P];
    __shared__ float red[64];
    int tid = threadIdx.x;
    for (int i = tid; i < POSI * 256; i += 256) {
        int c = i >> 8, r = i & 255, ly = r >> 4, lx = r & 15;
        float v = 0.f;
        if (ly >= 1 && ly <= HP && lx >= 1 && lx <= WP) v = posi[c*P + (ly-1)*WP + (lx-1)];
        ppad[c][ly][lx] = v;
    }
    __syncthreads();
    float s = 0.f, ss = 0.f;
    for (int idx = tid; idx < INTER * P; idx += 256) {
        int c = idx / P, p = idx - c*P, y = p / WP, x = p - (p/WP)*WP;
        float acc = 0.f;
        #pragma unroll
        for (int ci = 0; ci < POSI; ci++)
            #pragma unroll
            for (int dy = 0; dy < 3; dy++)
                #pragma unroll
                for (int dx = 0; dx < 3; dx++)
                    acc += w0[((c*POSI + ci)*3 + dy)*3 + dx] * ppad[ci][y+dy][x+dx];
        t[idx] = acc; s += acc; ss += acc*acc;
    }
    block_reduce2(s, ss, red, tid, 256);
    float mu = s / (float)(INTER*P);
    float var = ss / (float)(INTER*P) - mu*mu;
    float rstd = rsqrtf(var + EPSLN);
    for (int idx = tid; idx < INTER * P; idx += 256) {
        float v = (t[idx] - mu) * rstd * g0[idx] + b0[idx];
        a_out[idx] = v > 0.f ? v : 0.f;
    }
}

__global__ __launch_bounds__(256) void k_conv64(const float* __restrict__ a,
                                                const float* __restrict__ w,
                                                float* __restrict__ v) {
    __shared__ __align__(16) float as[INTER][16][16];
    int tid = threadIdx.x;
    for (int i = tid; i < INTER * 256; i += 256) {
        int c = i >> 8, r = i & 255, ly = r >> 4, lx = r & 15;
        float val = 0.f;
        if (ly >= 1 && ly <= HP && lx >= 1 && lx <= WP) val = a[c*P + (ly-1)*WP + (lx-1)];
        as[c][ly][lx] = val;
    }
    __syncthreads();
    int idx = blockIdx.x * 256 + tid;
    int c = idx / P, p = idx - c*P, y = p / WP, x = p - (p/WP)*WP;
    float acc = 0.f;
    for (int ci = 0; ci < INTER; ci++) {
        const float* wr = w + (c*INTER + ci)*9;
        acc += wr[0]*as[ci][y  ][x] + wr[1]*as[ci][y  ][x+1] + wr[2]*as[ci][y  ][x+2]
             + wr[3]*as[ci][y+1][x] + wr[4]*as[ci][y+1][x+1] + wr[5]*as[ci][y+1][x+2]
             + wr[6]*as[ci][y+2][x] + wr[7]*as[ci][y+2][x+1] + wr[8]*as[ci][y+2][x+2];
    }
    v[idx] = acc;
}

__global__ __launch_bounds__(1024) void k_lnrelu(const float* __restrict__ v,
                                                 const float* __restrict__ g,
                                                 const float* __restrict__ b,
                                                 float* __restrict__ a) {
    __shared__ float red[64];
    int tid = threadIdx.x;
    float s = 0.f, ss = 0.f;
    float vals[13];
    int cnt = 0;
    for (int idx = tid; idx < INTER * P; idx += 1024) {
        float x = v[idx]; vals[cnt++] = x; s += x; ss += x*x;
    }
    block_reduce2(s, ss, red, tid, 1024);
    float mu = s / (float)(INTER*P);
    float var = ss / (float)(INTER*P) - mu*mu;
    float rstd = rsqrtf(var + EPSLN);
    cnt = 0;
    for (int idx = tid; idx < INTER * P; idx += 1024) {
        float x = (vals[cnt++] - mu) * rstd * g[idx] + b[idx];
        a[idx] = x > 0.f ? x : 0.f;
    }
}

__global__ void k_im2col(const float* __restrict__ a, unsigned short* __restrict__ imc) {
    int idx = blockIdx.x * 256 + threadIdx.x;
    if (idx >= P * KIM) return;
    int p = idx / KIM, q = idx - p * KIM;
    int ci = q / 9, k = q - ci * 9;
    int y = p / WP + k / 3 - 1, x = p % WP + k % 3 - 1;
    float v = 0.f;
    if (y >= 0 && y < HP && x >= 0 && x < WP) v = a[ci * P + y * WP + x];
    imc[idx] = f2bf(v);
}

// final conv as MFMA GEMM; output layout wgt2[p][oc] with LDS-transposed coalesced stores.
// block = 2 waves x 16 oc; thread then streams full 64B lines per pixel.
__global__ __launch_bounds__(128) void k_gemm_wf(const unsigned short* __restrict__ wfb,
                                                 const unsigned short* __restrict__ imc,
                                                 unsigned short* __restrict__ wgt2) {
    __shared__ __align__(16) unsigned short ot[P * 40];   // [p][40] padded (15.7 KB)
    int tid = threadIdx.x;
    int w = tid >> 6, l = tid & 63;
    int quad = l >> 4, c16 = l & 15;
    int oc0 = blockIdx.x * 32 + w * 16;       // 383 blocks; last block: wave1 invalid
    f32x4 acc[13];
    #pragma unroll
    for (int f = 0; f < 13; f++) acc[f] = (f32x4)0.f;
    int arow = oc0 + c16; if (arow >= OUTCH) arow = OUTCH - 1;   // clamp, discard later
    const unsigned short* Arow = wfb + (size_t)arow * KIM + quad * 8;
    const unsigned short* Bb   = imc + quad * 8;
    for (int kk = 0; kk < 18; kk++) {
        int k0 = kk * 32;
        short8 af = *(const short8*)(Arow + k0);
        #pragma unroll
        for (int f = 0; f < 13; f++) {
            int p = f * 16 + c16;
            short8 bf = (short8)0;
            if (p < P) bf = *(const short8*)(Bb + (size_t)p * KIM + k0);
            acc[f] = __builtin_amdgcn_mfma_f32_16x16x32_bf16(af, bf, acc[f], 0, 0, 0);
        }
    }
    // transpose through LDS: lane writes 4 consecutive oc for its 13 p's
    #pragma unroll
    for (int f = 0; f < 13; f++) {
        int p = f * 16 + c16;
        if (p < P) {
            short4v sv;
            sv[0] = (short)f2bf(acc[f][0]);
            sv[1] = (short)f2bf(acc[f][1]);
            sv[2] = (short)f2bf(acc[f][2]);
            sv[3] = (short)f2bf(acc[f][3]);
            *(short4v*)(ot + p * 40 + w * 16 + quad * 4) = sv;
        }
    }
    __syncthreads();
    int oc_base = blockIdx.x * 32;
    int nvalid = OUTCH - oc_base; if (nvalid > 32) nvalid = 32;
    for (int p = tid; p < P; p += 128) {
        const short8* src = (const short8*)(ot + p * 40);
        unsigned short* dst = wgt2 + (size_t)p * OUTCH + oc_base;
        *(short8*)(dst)      = src[0];
        *(short8*)(dst + 8)  = src[1];
        if (nvalid > 16) {
            *(short8*)(dst + 16) = src[2];
            *(short8*)(dst + 24) = src[3];
        }
    }
}

// ---------------- tiled MFMA GEMM 1: h1t[n][m] = sum_k Wbin[m][k] Xt[n][k] ----------------
__global__ __launch_bounds__(256) void k_gemm_in(const unsigned short* __restrict__ A,
                                                 const unsigned short* __restrict__ B,
                                                 unsigned short* __restrict__ C) {
    __shared__ __align__(16) unsigned short As[128 * 32];
    __shared__ __align__(16) unsigned short Bs[128 * 32];
    int tid = threadIdx.x;
    int w = tid >> 6, lane = tid & 63, quad = lane >> 4, c16 = lane & 15;
    int m0 = blockIdx.x * 128, n0 = blockIdx.y * 128;
    int wm = (w & 1) * 64, wn = (w >> 1) * 64;
    f32x4 acc[4][4];
    #pragma unroll
    for (int i = 0; i < 4; i++)
        #pragma unroll
        for (int j = 0; j < 4; j++) acc[i][j] = (f32x4)0.f;

    for (int kc = 0; kc < 8; ++kc) {
        int k0 = kc * 32;
        if (kc) __syncthreads();
        #pragma unroll
        for (int i = tid; i < 512; i += 256) {
            int r = i >> 2, s = i & 3, q = (s - (r >> 1)) & 3;
            gl2lds16(A + (size_t)(m0 + r) * DIMC + k0 + q * 8, As + (i & ~63) * 8);
        }
        #pragma unroll
        for (int i = tid; i < 512; i += 256) {
            int r = i >> 2, s = i & 3, q = (s - (r >> 1)) & 3;
            gl2lds16(B + (size_t)(n0 + r) * DIMC + k0 + q * 8, Bs + (i & ~63) * 8);
        }
        __syncthreads();
        short8 af[4], bfr[4];
        #pragma unroll
        for (int i = 0; i < 4; i++) af[i] = fragld(As, wm + i * 16 + c16, quad);
        #pragma unroll
        for (int j = 0; j < 4; j++) bfr[j] = fragld(Bs, wn + j * 16 + c16, quad);
        #pragma unroll
        for (int i = 0; i < 4; i++)
            #pragma unroll
            for (int j = 0; j < 4; j++)
                acc[i][j] = __builtin_amdgcn_mfma_f32_16x16x32_bf16(af[i], bfr[j], acc[i][j], 0, 0, 0);
    }
    #pragma unroll
    for (int j = 0; j < 4; j++) {
        int n = n0 + wn + j * 16 + c16;
        unsigned short* dst = C + (size_t)n * CHN;
        #pragma unroll
        for (int i = 0; i < 4; i++) {
            int m = m0 + wm + i * 16 + quad * 4;
            if (m < CHN) {
                short4v sv;
                sv[0] = (short)f2bf(acc[i][j][0]);
                sv[1] = (short)f2bf(acc[i][j][1]);
                sv[2] = (short)f2bf(acc[i][j][2]);
                sv[3] = (short)f2bf(acc[i][j][3]);
                *(short4v*)(dst + m) = sv;
            }
        }
    }
}

// ---------------- fused tvconv + gelu-gate: block=(p, 16 b's) ----------------
// stages wgt2[p][oc] -> LDS [k][CHN] via scatter-transpose, compute loop vectorized
__global__ __launch_bounds__(256) void k_tvg(const unsigned short* __restrict__ h1t,
                                             const unsigned short* __restrict__ wgt2,
                                             unsigned short* __restrict__ hgt) {
    __shared__ __align__(16) unsigned short wl[9 * CHN];   // 24480 B, [k][CHN]
    int p = blockIdx.x, b0 = blockIdx.y * 16, tid = threadIdx.x;
    const unsigned short* wrow = wgt2 + (size_t)p * OUTCH;
    for (int i = tid * 8; i < OUTCH; i += 256 * 8) {
        short8 v = *(const short8*)(wrow + i);
        #pragma unroll
        for (int e = 0; e < 8; e++) {
            int oc = i + e;
            int ch = oc / 9, k = oc - ch * 9;
            wl[k * CHN + ch] = (unsigned short)v[e];
        }
    }
    int y = p / WP, x = p - (p / WP) * WP;
    int pn[9]; bool pv[9];
    #pragma unroll
    for (int k = 0; k < 9; k++) {
        int yy = y + k / 3 - 1, xx = x + (k % 3) - 1;
        pv[k] = (yy >= 0 && yy < HP && xx >= 0 && xx < WP);
        pn[k] = pv[k] ? yy * WP + xx : 0;
    }
    __syncthreads();
    for (int j = tid; j < 16 * 85; j += 256) {
        int bl = j / 85, c = (j - bl * 85) * 8;
        int b = b0 + bl;
        const unsigned short* hb = h1t + (size_t)b * P * CHN;
        float s1[8], s2[8];
        #pragma unroll
        for (int e = 0; e < 8; e++) { s1[e] = 0.f; s2[e] = 0.f; }
        #pragma unroll
        for (int k = 0; k < 9; k++) {
            if (!pv[k]) continue;
            const unsigned short* hr = hb + (size_t)pn[k] * CHN + c;
            short8 h1v = *(const short8*)hr;
            short8 h2v = *(const short8*)(hr + HID);
            short8 w1v = *(const short8*)(wl + k * CHN + c);
            short8 w2v = *(const short8*)(wl + k * CHN + HID + c);
            #pragma unroll
            for (int e = 0; e < 8; e++) {
                s1[e] += bf2f((unsigned short)w1v[e]) * bf2f((unsigned short)h1v[e]);
                s2[e] += bf2f((unsigned short)w2v[e]) * bf2f((unsigned short)h2v[e]);
            }
        }
        short8 o;
        #pragma unroll
        for (int e = 0; e < 8; e++) {
            float gl = 0.5f * s1[e] * (1.f + erff(s1[e] * 0.70710678118654752f));
            o[e] = (short)f2bf(gl * s2[e]);
        }
        *(short8*)(hgt + ((size_t)b * P + p) * KPAD + c) = o;
    }
    if (tid < 48) {
        int bl = tid / 3, z = (tid - bl * 3) * 8;
        *(short8*)(hgt + ((size_t)(b0 + bl) * P + p) * KPAD + HID + z) = (short8)0;
    }
}

// ---------------- tiled MFMA GEMM 2: out[m][n] = sum_k Wbout[m][k] hgt[n][k] ----------------
__global__ __launch_bounds__(256) void k_gemm_out(const unsigned short* __restrict__ A,
                                                  const unsigned short* __restrict__ B,
                                                  float* __restrict__ out) {
    __shared__ __align__(16) unsigned short As[64 * 32];
    __shared__ __align__(16) unsigned short Bs[128 * 32];
    int tid = threadIdx.x;
    int w = tid >> 6, lane = tid & 63, quad = lane >> 4, c16 = lane & 15;
    int m0 = blockIdx.x * 64, n0 = blockIdx.y * 128;
    int wm = (w & 1) * 32, wn = (w >> 1) * 64;
    f32x4 acc[2][4];
    #pragma unroll
    for (int i = 0; i < 2; i++)
        #pragma unroll
        for (int j = 0; j < 4; j++) acc[i][j] = (f32x4)0.f;

    for (int kc = 0; kc < 22; ++kc) {
        int k0 = kc * 32;
        if (kc) __syncthreads();
        {
            int i = tid;
            int r = i >> 2, s = i & 3, q = (s - (r >> 1)) & 3;
            gl2lds16(A + (size_t)(m0 + r) * KPAD + k0 + q * 8, As + (i & ~63) * 8);
        }
        #pragma unroll
        for (int i = tid; i < 512; i += 256) {
            int r = i >> 2, s = i & 3, q = (s - (r >> 1)) & 3;
            gl2lds16(B + (size_t)(n0 + r) * KPAD + k0 + q * 8, Bs + (i & ~63) * 8);
        }
        __syncthreads();
        short8 af[2], bfr[4];
        #pragma unroll
        for (int i = 0; i < 2; i++) af[i] = fragld(As, wm + i * 16 + c16, quad);
        #pragma unroll
        for (int j = 0; j < 4; j++) bfr[j] = fragld(Bs, wn + j * 16 + c16, quad);
        #pragma unroll
        for (int i = 0; i < 2; i++)
            #pragma unroll
            for (int j = 0; j < 4; j++)
                acc[i][j] = __builtin_amdgcn_mfma_f32_16x16x32_bf16(af[i], bfr[j], acc[i][j], 0, 0, 0);
    }
    #pragma unroll
    for (int j = 0; j < 4; j++) {
        int n = n0 + wn + j * 16 + c16;
        int b = n / P, pp = n - b * P;
        #pragma unroll
        for (int i = 0; i < 2; i++) {
            int m = m0 + wm + i * 16 + quad * 4;
            #pragma unroll
            for (int r = 0; r < 4; r++)
                out[((size_t)b * DIMC + m + r) * P + pp] = acc[i][j][r];
        }
    }
}

extern "C" void kernel_launch(void* const* d_in, const int* in_sizes, int n_in,
                              void* d_out, int out_size, void* d_ws, size_t ws_size,
                              hipStream_t stream) {
    (void)in_sizes; (void)n_in; (void)out_size; (void)ws_size;
    const float* x     = (const float*)d_in[0];
    const float* W_in  = (const float*)d_in[1];
    const float* posi  = (const float*)d_in[2];
    const float* w0    = (const float*)d_in[3];
    const float* g0    = (const float*)d_in[4];
    const float* b0    = (const float*)d_in[5];
    const float* w1    = (const float*)d_in[6];
    const float* g1    = (const float*)d_in[7];
    const float* b1    = (const float*)d_in[8];
    const float* w2    = (const float*)d_in[9];
    const float* g2    = (const float*)d_in[10];
    const float* b2    = (const float*)d_in[11];
    const float* wf    = (const float*)d_in[12];
    const float* W_out = (const float*)d_in[13];
    float* out = (float*)d_out;
    char* ws = (char*)d_ws;

    unsigned short* Wbin  = (unsigned short*)(ws + OFS_WBIN);
    unsigned short* Wbout = (unsigned short*)(ws + OFS_WBOUT);
    unsigned short* Xt    = (unsigned short*)(ws + OFS_XT);
    float*          a_buf = (float*)(ws + OFS_ABUF);
    float*          v_buf = (float*)(ws + OFS_VBUF);
    unsigned short* wgt2  = (unsigned short*)(ws + OFS_WGTT);
    unsigned short* h1t   = (unsigned short*)(ws + OFS_H1T);
    unsigned short* hgt   = (unsigned short*)(ws + OFS_HGT);
    unsigned short* wfb   = (unsigned short*)(ws + OFS_WFB);
    unsigned short* imc   = (unsigned short*)(ws + OFS_IMC);

    // casts / transposes
    k_cast_win <<<(MPADIN*DIMC + 255)/256, 256, 0, stream>>>(W_in, Wbin);
    k_cast_wout<<<(DIMC*KPAD + 255)/256, 256, 0, stream>>>(W_out, Wbout);
    k_cast_wf  <<<(OUTCH*KIM/4 + 255)/256, 256, 0, stream>>>(wf, wfb);
    k_xt       <<<dim3(DIMC/32, BATCH), 256, 0, stream>>>(x, Xt);

    // weight-generator network
    k_stage0<<<1, 256, 0, stream>>>(posi, w0, g0, b0, a_buf);
    k_conv64<<<49, 256, 0, stream>>>(a_buf, w1, v_buf);
    k_lnrelu<<<1, 1024, 0, stream>>>(v_buf, g1, b1, a_buf);
    k_conv64<<<49, 256, 0, stream>>>(a_buf, w2, v_buf);
    k_lnrelu<<<1, 1024, 0, stream>>>(v_buf, g2, b2, a_buf);
    k_im2col<<<(P*KIM + 255)/256, 256, 0, stream>>>(a_buf, imc);
    k_gemm_wf<<<(OUTCH + 31)/32, 128, 0, stream>>>(wfb, imc, wgt2);

    // main path (tiled MFMA)
    k_gemm_in <<<dim3(MPADIN/128, (BATCH*P)/128), 256, 0, stream>>>(Wbin, Xt, h1t);
    k_tvg     <<<dim3(P, BATCH/16), 256, 0, stream>>>(h1t, wgt2, hgt);
    k_gemm_out<<<dim3(DIMC/64, (BATCH*P)/128), 256, 0, stream>>>(Wbout, hgt, out);
}

// Round 6
// 330.256 us; speedup vs baseline: 2.9947x; 1.0718x over previous
//
#include <hip/hip_runtime.h>
#include <math.h>

// ---- problem constants ----
#define DIMC   256
#define HID    680
#define CHN    1360
#define HP     14
#define WP     14
#define P      196
#define POSI   4
#define INTER  64
#define BATCH  64
#define KPAD   704          // 680 padded to 22*32
#define OUTCH  12240        // CHN*9
#define OCPAD  12288        // 12240 padded to 192*64
#define KIM    576          // INTER*9
#define MPADIN 1408         // 1360 padded to 11*128
#define EPSLN  1e-5f

typedef __attribute__((ext_vector_type(8))) short short8;
typedef __attribute__((ext_vector_type(4))) short short4v;
typedef __attribute__((ext_vector_type(4))) float f32x4;

// ---- workspace layout (bytes) ----
#define OFS_WBIN  0u                  // 1408*256*2   = 720896
#define OFS_WBOUT 720896u             // 256*704*2    = 360448
#define OFS_XT    1081344u            // 64*196*256*2 = 6422528
#define OFS_ABUF  7503872u            // 12544*4
#define OFS_VBUF  7554048u            // 12544*4
#define OFS_WGTT  7604224u            // 196*12240*2 = 4798080  ([p][oc] layout)
#define OFS_H1T   12402304u           // 64*196*1360*2 = 34127872
#define OFS_HGT   46530176u           // 64*196*704*2  = 17661952
#define OFS_WFB   64192128u           // 12288*576*2   = 14155776 (oc-padded)
#define OFS_IMC   78347904u           // 196*576*2     = 225792  (end ~78.6MB)

__device__ __forceinline__ unsigned short f2bf(float f) {
    union { float f; unsigned u; } v; v.f = f;
    unsigned u = v.u;
    return (unsigned short)((u + 0x7FFFu + ((u >> 16) & 1u)) >> 16);   // RNE
}
__device__ __forceinline__ float bf2f(unsigned short h) {
    union { unsigned u; float f; } v; v.u = ((unsigned)h) << 16; return v.f;
}

// async 16B global->LDS (wave-uniform LDS base + lane*16)
__device__ __forceinline__ void gl2lds16(const unsigned short* g, unsigned short* l) {
    __builtin_amdgcn_global_load_lds(
        (const __attribute__((address_space(1))) unsigned int*)g,
        (__attribute__((address_space(3))) unsigned int*)l, 16, 0, 0);
}
// swizzled fragment read: row-major LDS tile, row stride 32 bf16, slot-rotated 16B pieces
__device__ __forceinline__ short8 fragld(const unsigned short* S, int row, int quad) {
    int slot = ((row >> 1) + quad) & 3;
    return *(const short8*)(S + row * 32 + slot * 8);
}

// ---------------- small casts ----------------
__global__ void k_cast_win(const float* __restrict__ W, unsigned short* __restrict__ Wb) {
    int i = blockIdx.x * 256 + threadIdx.x;
    if (i < MPADIN * DIMC) Wb[i] = (i < CHN * DIMC) ? f2bf(W[i]) : (unsigned short)0;
}
__global__ void k_cast_wout(const float* __restrict__ W, unsigned short* __restrict__ Wb) {
    int i = blockIdx.x * 256 + threadIdx.x;
    if (i < DIMC * KPAD) {
        int o = i / KPAD, k = i - o * KPAD;
        Wb[i] = f2bf(k < HID ? W[o * HID + k] : 0.f);
    }
}
__global__ void k_cast_wf(const float* __restrict__ wf, unsigned short* __restrict__ wfb) {
    int i = (blockIdx.x * 256 + threadIdx.x) * 4;
    if (i < OCPAD * KIM) {
        short4v s = (short4v)0;
        if (i < OUTCH * KIM) {
            float4 v = *(const float4*)(wf + i);
            s[0] = (short)f2bf(v.x); s[1] = (short)f2bf(v.y);
            s[2] = (short)f2bf(v.z); s[3] = (short)f2bf(v.w);
        }
        *(short4v*)(wfb + i) = s;
    }
}
// x [64][256][196] f32 -> Xt [64][196][256] bf16
__global__ __launch_bounds__(256) void k_xt(const float* __restrict__ x,
                                            unsigned short* __restrict__ Xt) {
    __shared__ float xs[32][197];
    int b = blockIdx.y, c0 = blockIdx.x * 32, tid = threadIdx.x;
    for (int i = tid; i < 32 * P; i += 256) {
        int ci = i / P, pp = i - ci * P;
        xs[ci][pp] = x[((size_t)b * DIMC + c0 + ci) * P + pp];
    }
    __syncthreads();
    for (int j = tid; j < P * 32; j += 256) {
        int ci = j & 31, pp = j >> 5;
        Xt[((size_t)b * P + pp) * DIMC + c0 + ci] = f2bf(xs[ci][pp]);
    }
}

// ---------------- weight-generator net head (unchanged) ----------------
__device__ __forceinline__ void block_reduce2(float& s, float& ss, float* red, int tid, int nthreads) {
    #pragma unroll
    for (int off = 32; off > 0; off >>= 1) {
        s  += __shfl_down(s, off);
        ss += __shfl_down(ss, off);
    }
    int wid = tid >> 6, nw = nthreads >> 6;
    if ((tid & 63) == 0) { red[wid*2] = s; red[wid*2+1] = ss; }
    __syncthreads();
    if (tid == 0) {
        float S = 0.f, SS = 0.f;
        for (int i = 0; i < nw; i++) { S += red[i*2]; SS += red[i*2+1]; }
        red[0] = S; red[1] = SS;
    }
    __syncthreads();
    s = red[0]; ss = red[1];
}

__global__ __launch_bounds__(256) void k_stage0(const float* __restrict__ posi,
                                                const float* __restrict__ w0,
                                                const float* __restrict__ g0,
                                                const float* __restrict__ b0,
                                                float* __restrict__ a_out) {
    __shared__ __align__(16) float ppad[POSI][16][16];
    __shared__ __align__(16) float t[INTER * P];
    __shared__ float red[64];
    int tid = threadIdx.x;
    for (int i = tid; i < POSI * 256; i += 256) {
        int c = i >> 8, r = i & 255, ly = r >> 4, lx = r & 15;
        float v = 0.f;
        if (ly >= 1 && ly <= HP && lx >= 1 && lx <= WP) v = posi[c*P + (ly-1)*WP + (lx-1)];
        ppad[c][ly][lx] = v;
    }
    __syncthreads();
    float s = 0.f, ss = 0.f;
    for (int idx = tid; idx < INTER * P; idx += 256) {
        int c = idx / P, p = idx - c*P, y = p / WP, x = p - (p/WP)*WP;
        float acc = 0.f;
        #pragma unroll
        for (int ci = 0; ci < POSI; ci++)
            #pragma unroll
            for (int dy = 0; dy < 3; dy++)
                #pragma unroll
                for (int dx = 0; dx < 3; dx++)
                    acc += w0[((c*POSI + ci)*3 + dy)*3 + dx] * ppad[ci][y+dy][x+dx];
        t[idx] = acc; s += acc; ss += acc*acc;
    }
    block_reduce2(s, ss, red, tid, 256);
    float mu = s / (float)(INTER*P);
    float var = ss / (float)(INTER*P) - mu*mu;
    float rstd = rsqrtf(var + EPSLN);
    for (int idx = tid; idx < INTER * P; idx += 256) {
        float v = (t[idx] - mu) * rstd * g0[idx] + b0[idx];
        a_out[idx] = v > 0.f ? v : 0.f;
    }
}

__global__ __launch_bounds__(256) void k_conv64(const float* __restrict__ a,
                                                const float* __restrict__ w,
                                                float* __restrict__ v) {
    __shared__ __align__(16) float as[INTER][16][16];
    int tid = threadIdx.x;
    for (int i = tid; i < INTER * 256; i += 256) {
        int c = i >> 8, r = i & 255, ly = r >> 4, lx = r & 15;
        float val = 0.f;
        if (ly >= 1 && ly <= HP && lx >= 1 && lx <= WP) val = a[c*P + (ly-1)*WP + (lx-1)];
        as[c][ly][lx] = val;
    }
    __syncthreads();
    int idx = blockIdx.x * 256 + tid;
    int c = idx / P, p = idx - c*P, y = p / WP, x = p - (p/WP)*WP;
    float acc = 0.f;
    for (int ci = 0; ci < INTER; ci++) {
        const float* wr = w + (c*INTER + ci)*9;
        acc += wr[0]*as[ci][y  ][x] + wr[1]*as[ci][y  ][x+1] + wr[2]*as[ci][y  ][x+2]
             + wr[3]*as[ci][y+1][x] + wr[4]*as[ci][y+1][x+1] + wr[5]*as[ci][y+1][x+2]
             + wr[6]*as[ci][y+2][x] + wr[7]*as[ci][y+2][x+1] + wr[8]*as[ci][y+2][x+2];
    }
    v[idx] = acc;
}

__global__ __launch_bounds__(1024) void k_lnrelu(const float* __restrict__ v,
                                                 const float* __restrict__ g,
                                                 const float* __restrict__ b,
                                                 float* __restrict__ a) {
    __shared__ float red[64];
    int tid = threadIdx.x;
    float s = 0.f, ss = 0.f;
    float vals[13];
    int cnt = 0;
    for (int idx = tid; idx < INTER * P; idx += 1024) {
        float x = v[idx]; vals[cnt++] = x; s += x; ss += x*x;
    }
    block_reduce2(s, ss, red, tid, 1024);
    float mu = s / (float)(INTER*P);
    float var = ss / (float)(INTER*P) - mu*mu;
    float rstd = rsqrtf(var + EPSLN);
    cnt = 0;
    for (int idx = tid; idx < INTER * P; idx += 1024) {
        float x = (vals[cnt++] - mu) * rstd * g[idx] + b[idx];
        a[idx] = x > 0.f ? x : 0.f;
    }
}

__global__ void k_im2col(const float* __restrict__ a, unsigned short* __restrict__ imc) {
    int idx = blockIdx.x * 256 + threadIdx.x;
    if (idx >= P * KIM) return;
    int p = idx / KIM, q = idx - p * KIM;
    int ci = q / 9, k = q - ci * 9;
    int y = p / WP + k / 3 - 1, x = p % WP + k % 3 - 1;
    float v = 0.f;
    if (y >= 0 && y < HP && x >= 0 && x < WP) v = a[ci * P + y * WP + x];
    imc[idx] = f2bf(v);
}

// final conv as LDS-staged tiled MFMA GEMM: wgt2[p][oc] = sum_q wfb[oc][q] imc[p][q]
// block = 64 oc x 196 p, 4 waves (16 oc each), 18 K-chunks of 32 via global_load_lds
__global__ __launch_bounds__(256) void k_gemm_wf(const unsigned short* __restrict__ wfb,
                                                 const unsigned short* __restrict__ imc,
                                                 unsigned short* __restrict__ wgt2) {
    __shared__ __align__(16) unsigned short As[64 * 32];    // 4 KB
    __shared__ __align__(16) unsigned short Bs[208 * 32];   // 13.3 KB (rows 196..207 zero)
    __shared__ __align__(16) unsigned short ot[P * 72];     // 28.2 KB output transpose
    int tid = threadIdx.x;
    int w = tid >> 6, lane = tid & 63, quad = lane >> 4, c16 = lane & 15;
    int m0 = blockIdx.x * 64;                               // 192 blocks
    // zero pad rows of Bs once; they stay zero (staging never touches them)
    for (int i = tid; i < 48; i += 256)
        *(short8*)(Bs + 196 * 32 + i * 8) = (short8)0;
    f32x4 acc[13];
    #pragma unroll
    for (int f = 0; f < 13; f++) acc[f] = (f32x4)0.f;

    for (int kc = 0; kc < 18; ++kc) {
        int k0 = kc * 32;
        if (kc) __syncthreads();
        {                                                   // A: 64 rows x 4 pieces
            int i = tid;
            int r = i >> 2, s = i & 3, q = (s - (r >> 1)) & 3;
            gl2lds16(wfb + (size_t)(m0 + r) * KIM + k0 + q * 8, As + (i & ~63) * 8);
        }
        for (int i = tid; i < 784; i += 256) {              // B: 196 rows x 4 pieces
            int r = i >> 2, s = i & 3, q = (s - (r >> 1)) & 3;
            gl2lds16(imc + (size_t)r * KIM + k0 + q * 8, Bs + (i & ~63) * 8);
        }
        __syncthreads();
        short8 af = fragld(As, w * 16 + c16, quad);
        #pragma unroll
        for (int f = 0; f < 13; f++) {
            short8 bf = fragld(Bs, f * 16 + c16, quad);
            acc[f] = __builtin_amdgcn_mfma_f32_16x16x32_bf16(af, bf, acc[f], 0, 0, 0);
        }
    }
    __syncthreads();
    #pragma unroll
    for (int f = 0; f < 13; f++) {
        int p = f * 16 + c16;
        if (p < P) {
            short4v sv;
            sv[0] = (short)f2bf(acc[f][0]);
            sv[1] = (short)f2bf(acc[f][1]);
            sv[2] = (short)f2bf(acc[f][2]);
            sv[3] = (short)f2bf(acc[f][3]);
            *(short4v*)(ot + p * 72 + w * 16 + quad * 4) = sv;
        }
    }
    __syncthreads();
    int nvalid = OUTCH - m0; if (nvalid > 64) nvalid = 64;  // last block: 16
    for (int p = tid; p < P; p += 256) {
        const short8* src = (const short8*)(ot + p * 72);
        unsigned short* dst = wgt2 + (size_t)p * OUTCH + m0;
        #pragma unroll
        for (int j = 0; j < 8; j++)
            if (j * 8 < nvalid) *(short8*)(dst + j * 8) = src[j];
    }
}

// ---------------- tiled MFMA GEMM 1: h1t[n][m] = sum_k Wbin[m][k] Xt[n][k] ----------------
__global__ __launch_bounds__(256) void k_gemm_in(const unsigned short* __restrict__ A,
                                                 const unsigned short* __restrict__ B,
                                                 unsigned short* __restrict__ C) {
    __shared__ __align__(16) unsigned short As[128 * 32];
    __shared__ __align__(16) unsigned short Bs[128 * 32];
    int tid = threadIdx.x;
    int w = tid >> 6, lane = tid & 63, quad = lane >> 4, c16 = lane & 15;
    int m0 = blockIdx.x * 128, n0 = blockIdx.y * 128;
    int wm = (w & 1) * 64, wn = (w >> 1) * 64;
    f32x4 acc[4][4];
    #pragma unroll
    for (int i = 0; i < 4; i++)
        #pragma unroll
        for (int j = 0; j < 4; j++) acc[i][j] = (f32x4)0.f;

    for (int kc = 0; kc < 8; ++kc) {
        int k0 = kc * 32;
        if (kc) __syncthreads();
        #pragma unroll
        for (int i = tid; i < 512; i += 256) {
            int r = i >> 2, s = i & 3, q = (s - (r >> 1)) & 3;
            gl2lds16(A + (size_t)(m0 + r) * DIMC + k0 + q * 8, As + (i & ~63) * 8);
        }
        #pragma unroll
        for (int i = tid; i < 512; i += 256) {
            int r = i >> 2, s = i & 3, q = (s - (r >> 1)) & 3;
            gl2lds16(B + (size_t)(n0 + r) * DIMC + k0 + q * 8, Bs + (i & ~63) * 8);
        }
        __syncthreads();
        short8 af[4], bfr[4];
        #pragma unroll
        for (int i = 0; i < 4; i++) af[i] = fragld(As, wm + i * 16 + c16, quad);
        #pragma unroll
        for (int j = 0; j < 4; j++) bfr[j] = fragld(Bs, wn + j * 16 + c16, quad);
        #pragma unroll
        for (int i = 0; i < 4; i++)
            #pragma unroll
            for (int j = 0; j < 4; j++)
                acc[i][j] = __builtin_amdgcn_mfma_f32_16x16x32_bf16(af[i], bfr[j], acc[i][j], 0, 0, 0);
    }
    #pragma unroll
    for (int j = 0; j < 4; j++) {
        int n = n0 + wn + j * 16 + c16;
        unsigned short* dst = C + (size_t)n * CHN;
        #pragma unroll
        for (int i = 0; i < 4; i++) {
            int m = m0 + wm + i * 16 + quad * 4;
            if (m < CHN) {
                short4v sv;
                sv[0] = (short)f2bf(acc[i][j][0]);
                sv[1] = (short)f2bf(acc[i][j][1]);
                sv[2] = (short)f2bf(acc[i][j][2]);
                sv[3] = (short)f2bf(acc[i][j][3]);
                *(short4v*)(dst + m) = sv;
            }
        }
    }
}

// ---------------- fused tvconv + gelu-gate: block=(p, 16 b's) ----------------
__global__ __launch_bounds__(256) void k_tvg(const unsigned short* __restrict__ h1t,
                                             const unsigned short* __restrict__ wgt2,
                                             unsigned short* __restrict__ hgt) {
    __shared__ __align__(16) unsigned short wl[9 * CHN];   // 24480 B, [k][CHN]
    int p = blockIdx.x, b0 = blockIdx.y * 16, tid = threadIdx.x;
    const unsigned short* wrow = wgt2 + (size_t)p * OUTCH;
    for (int i = tid * 8; i < OUTCH; i += 256 * 8) {
        short8 v = *(const short8*)(wrow + i);
        #pragma unroll
        for (int e = 0; e < 8; e++) {
            int oc = i + e;
            int ch = oc / 9, k = oc - ch * 9;
            wl[k * CHN + ch] = (unsigned short)v[e];
        }
    }
    int y = p / WP, x = p - (p / WP) * WP;
    int pn[9]; bool pv[9];
    #pragma unroll
    for (int k = 0; k < 9; k++) {
        int yy = y + k / 3 - 1, xx = x + (k % 3) - 1;
        pv[k] = (yy >= 0 && yy < HP && xx >= 0 && xx < WP);
        pn[k] = pv[k] ? yy * WP + xx : 0;
    }
    __syncthreads();
    for (int j = tid; j < 16 * 85; j += 256) {
        int bl = j / 85, c = (j - bl * 85) * 8;
        int b = b0 + bl;
        const unsigned short* hb = h1t + (size_t)b * P * CHN;
        float s1[8], s2[8];
        #pragma unroll
        for (int e = 0; e < 8; e++) { s1[e] = 0.f; s2[e] = 0.f; }
        #pragma unroll
        for (int k = 0; k < 9; k++) {
            if (!pv[k]) continue;
            const unsigned short* hr = hb + (size_t)pn[k] * CHN + c;
            short8 h1v = *(const short8*)hr;
            short8 h2v = *(const short8*)(hr + HID);
            short8 w1v = *(const short8*)(wl + k * CHN + c);
            short8 w2v = *(const short8*)(wl + k * CHN + HID + c);
            #pragma unroll
            for (int e = 0; e < 8; e++) {
                s1[e] += bf2f((unsigned short)w1v[e]) * bf2f((unsigned short)h1v[e]);
                s2[e] += bf2f((unsigned short)w2v[e]) * bf2f((unsigned short)h2v[e]);
            }
        }
        short8 o;
        #pragma unroll
        for (int e = 0; e < 8; e++) {
            float gl = 0.5f * s1[e] * (1.f + erff(s1[e] * 0.70710678118654752f));
            o[e] = (short)f2bf(gl * s2[e]);
        }
        *(short8*)(hgt + ((size_t)b * P + p) * KPAD + c) = o;
    }
    if (tid < 48) {
        int bl = tid / 3, z = (tid - bl * 3) * 8;
        *(short8*)(hgt + ((size_t)(b0 + bl) * P + p) * KPAD + HID + z) = (short8)0;
    }
}

// ---------------- tiled MFMA GEMM 2: out[m][n] = sum_k Wbout[m][k] hgt[n][k] ----------------
__global__ __launch_bounds__(256) void k_gemm_out(const unsigned short* __restrict__ A,
                                                  const unsigned short* __restrict__ B,
                                                  float* __restrict__ out) {
    __shared__ __align__(16) unsigned short As[64 * 32];
    __shared__ __align__(16) unsigned short Bs[128 * 32];
    int tid = threadIdx.x;
    int w = tid >> 6, lane = tid & 63, quad = lane >> 4, c16 = lane & 15;
    int m0 = blockIdx.x * 64, n0 = blockIdx.y * 128;
    int wm = (w & 1) * 32, wn = (w >> 1) * 64;
    f32x4 acc[2][4];
    #pragma unroll
    for (int i = 0; i < 2; i++)
        #pragma unroll
        for (int j = 0; j < 4; j++) acc[i][j] = (f32x4)0.f;

    for (int kc = 0; kc < 22; ++kc) {
        int k0 = kc * 32;
        if (kc) __syncthreads();
        {
            int i = tid;
            int r = i >> 2, s = i & 3, q = (s - (r >> 1)) & 3;
            gl2lds16(A + (size_t)(m0 + r) * KPAD + k0 + q * 8, As + (i & ~63) * 8);
        }
        #pragma unroll
        for (int i = tid; i < 512; i += 256) {
            int r = i >> 2, s = i & 3, q = (s - (r >> 1)) & 3;
            gl2lds16(B + (size_t)(n0 + r) * KPAD + k0 + q * 8, Bs + (i & ~63) * 8);
        }
        __syncthreads();
        short8 af[2], bfr[4];
        #pragma unroll
        for (int i = 0; i < 2; i++) af[i] = fragld(As, wm + i * 16 + c16, quad);
        #pragma unroll
        for (int j = 0; j < 4; j++) bfr[j] = fragld(Bs, wn + j * 16 + c16, quad);
        #pragma unroll
        for (int i = 0; i < 2; i++)
            #pragma unroll
            for (int j = 0; j < 4; j++)
                acc[i][j] = __builtin_amdgcn_mfma_f32_16x16x32_bf16(af[i], bfr[j], acc[i][j], 0, 0, 0);
    }
    #pragma unroll
    for (int j = 0; j < 4; j++) {
        int n = n0 + wn + j * 16 + c16;
        int b = n / P, pp = n - b * P;
        #pragma unroll
        for (int i = 0; i < 2; i++) {
            int m = m0 + wm + i * 16 + quad * 4;
            #pragma unroll
            for (int r = 0; r < 4; r++)
                out[((size_t)b * DIMC + m + r) * P + pp] = acc[i][j][r];
        }
    }
}

extern "C" void kernel_launch(void* const* d_in, const int* in_sizes, int n_in,
                              void* d_out, int out_size, void* d_ws, size_t ws_size,
                              hipStream_t stream) {
    (void)in_sizes; (void)n_in; (void)out_size; (void)ws_size;
    const float* x     = (const float*)d_in[0];
    const float* W_in  = (const float*)d_in[1];
    const float* posi  = (const float*)d_in[2];
    const float* w0    = (const float*)d_in[3];
    const float* g0    = (const float*)d_in[4];
    const float* b0    = (const float*)d_in[5];
    const float* w1    = (const float*)d_in[6];
    const float* g1    = (const float*)d_in[7];
    const float* b1    = (const float*)d_in[8];
    const float* w2    = (const float*)d_in[9];
    const float* g2    = (const float*)d_in[10];
    const float* b2    = (const float*)d_in[11];
    const float* wf    = (const float*)d_in[12];
    const float* W_out = (const float*)d_in[13];
    float* out = (float*)d_out;
    char* ws = (char*)d_ws;

    unsigned short* Wbin  = (unsigned short*)(ws + OFS_WBIN);
    unsigned short* Wbout = (unsigned short*)(ws + OFS_WBOUT);
    unsigned short* Xt    = (unsigned short*)(ws + OFS_XT);
    float*          a_buf = (float*)(ws + OFS_ABUF);
    float*          v_buf = (float*)(ws + OFS_VBUF);
    unsigned short* wgt2  = (unsigned short*)(ws + OFS_WGTT);
    unsigned short* h1t   = (unsigned short*)(ws + OFS_H1T);
    unsigned short* hgt   = (unsigned short*)(ws + OFS_HGT);
    unsigned short* wfb   = (unsigned short*)(ws + OFS_WFB);
    unsigned short* imc   = (unsigned short*)(ws + OFS_IMC);

    // casts / transposes
    k_cast_win <<<(MPADIN*DIMC + 255)/256, 256, 0, stream>>>(W_in, Wbin);
    k_cast_wout<<<(DIMC*KPAD + 255)/256, 256, 0, stream>>>(W_out, Wbout);
    k_cast_wf  <<<(OCPAD*KIM/4 + 255)/256, 256, 0, stream>>>(wf, wfb);
    k_xt       <<<dim3(DIMC/32, BATCH), 256, 0, stream>>>(x, Xt);

    // weight-generator network
    k_stage0<<<1, 256, 0, stream>>>(posi, w0, g0, b0, a_buf);
    k_conv64<<<49, 256, 0, stream>>>(a_buf, w1, v_buf);
    k_lnrelu<<<1, 1024, 0, stream>>>(v_buf, g1, b1, a_buf);
    k_conv64<<<49, 256, 0, stream>>>(a_buf, w2, v_buf);
    k_lnrelu<<<1, 1024, 0, stream>>>(v_buf, g2, b2, a_buf);
    k_im2col<<<(P*KIM + 255)/256, 256, 0, stream>>>(a_buf, imc);
    k_gemm_wf<<<OCPAD/64, 256, 0, stream>>>(wfb, imc, wgt2);

    // main path (tiled MFMA)
    k_gemm_in <<<dim3(MPADIN/128, (BATCH*P)/128), 256, 0, stream>>>(Wbin, Xt, h1t);
    k_tvg     <<<dim3(P, BATCH/16), 256, 0, stream>>>(h1t, wgt2, hgt);
    k_gemm_out<<<dim3(DIMC/64, (BATCH*P)/128), 256, 0, stream>>>(Wbout, hgt, out);
}

// Round 7
// 321.170 us; speedup vs baseline: 3.0794x; 1.0283x over previous
//
#include <hip/hip_runtime.h>
#include <math.h>

// ---- problem constants ----
#define DIMC   256
#define HID    680
#define CHN    1360
#define HP     14
#define WP     14
#define P      196
#define POSI   4
#define INTER  64
#define BATCH  64
#define KPAD   704          // 680 padded to 22*32
#define OUTCH  12240        // CHN*9
#define MW     1408         // per-k-plane channel pad (22*64)
#define MTOT   12672        // 9*MW
#define KIM    576          // INTER*9
#define MPADIN 1408         // 1360 padded to 11*128
#define EPSLN  1e-5f

typedef __attribute__((ext_vector_type(8))) short short8;
typedef __attribute__((ext_vector_type(4))) short short4v;
typedef __attribute__((ext_vector_type(4))) float f32x4;

// ---- workspace layout (bytes) ----
#define OFS_WBIN  0u                  // 1408*256*2   = 720896
#define OFS_WBOUT 720896u             // 256*704*2    = 360448
#define OFS_XT    1081344u            // 64*196*256*2 = 6422528
#define OFS_ABUF  7503872u            // 12544*4
#define OFS_VBUF  7554048u            // 12544*4
#define OFS_WGTT  7604224u            // 196*9*1360*2 = 4798080  ([p][k][ch] layout)
#define OFS_H1T   12402304u           // 64*196*1360*2 = 34127872
#define OFS_HGT   46530176u           // 64*196*704*2  = 17661952
#define OFS_WFB   64192128u           // 12672*576*2   = 14598144 (k-major, padded)
#define OFS_IMC   78790272u           // 196*576*2     = 225792  (end ~79.0MB)

__device__ __forceinline__ unsigned short f2bf(float f) {
    union { float f; unsigned u; } v; v.f = f;
    unsigned u = v.u;
    return (unsigned short)((u + 0x7FFFu + ((u >> 16) & 1u)) >> 16);   // RNE
}
__device__ __forceinline__ float bf2f(unsigned short h) {
    union { unsigned u; float f; } v; v.u = ((unsigned)h) << 16; return v.f;
}

// async 16B global->LDS (wave-uniform LDS base + lane*16)
__device__ __forceinline__ void gl2lds16(const unsigned short* g, unsigned short* l) {
    __builtin_amdgcn_global_load_lds(
        (const __attribute__((address_space(1))) unsigned int*)g,
        (__attribute__((address_space(3))) unsigned int*)l, 16, 0, 0);
}
// swizzled fragment read: row-major LDS tile, row stride 32 bf16, slot-rotated 16B pieces
__device__ __forceinline__ short8 fragld(const unsigned short* S, int row, int quad) {
    int slot = ((row >> 1) + quad) & 3;
    return *(const short8*)(S + row * 32 + slot * 8);
}

// ---------------- small casts ----------------
__global__ void k_cast_win(const float* __restrict__ W, unsigned short* __restrict__ Wb) {
    int i = blockIdx.x * 256 + threadIdx.x;
    if (i < MPADIN * DIMC) Wb[i] = (i < CHN * DIMC) ? f2bf(W[i]) : (unsigned short)0;
}
__global__ void k_cast_wout(const float* __restrict__ W, unsigned short* __restrict__ Wb) {
    int i = blockIdx.x * 256 + threadIdx.x;
    if (i < DIMC * KPAD) {
        int o = i / KPAD, k = i - o * KPAD;
        Wb[i] = f2bf(k < HID ? W[o * HID + k] : 0.f);
    }
}
// wf [oc=ch*9+k][q] f32 -> wfb [m=k*1408+ch][q] bf16 (k-major permute + pad)
__global__ void k_cast_wf(const float* __restrict__ wf, unsigned short* __restrict__ wfb) {
    int i = (blockIdx.x * 256 + threadIdx.x) * 4;
    if (i >= MTOT * KIM) return;
    int m = i / KIM, q = i - m * KIM;
    int kk = m / MW, ch = m - kk * MW;
    short4v s = (short4v)0;
    if (ch < CHN) {
        float4 v = *(const float4*)(wf + ((size_t)(ch * 9 + kk)) * KIM + q);
        s[0] = (short)f2bf(v.x); s[1] = (short)f2bf(v.y);
        s[2] = (short)f2bf(v.z); s[3] = (short)f2bf(v.w);
    }
    *(short4v*)(wfb + i) = s;
}
// x [64][256][196] f32 -> Xt [64][196][256] bf16
__global__ __launch_bounds__(256) void k_xt(const float* __restrict__ x,
                                            unsigned short* __restrict__ Xt) {
    __shared__ float xs[32][197];
    int b = blockIdx.y, c0 = blockIdx.x * 32, tid = threadIdx.x;
    for (int i = tid; i < 32 * P; i += 256) {
        int ci = i / P, pp = i - ci * P;
        xs[ci][pp] = x[((size_t)b * DIMC + c0 + ci) * P + pp];
    }
    __syncthreads();
    for (int j = tid; j < P * 32; j += 256) {
        int ci = j & 31, pp = j >> 5;
        Xt[((size_t)b * P + pp) * DIMC + c0 + ci] = f2bf(xs[ci][pp]);
    }
}

// ---------------- weight-generator net head (unchanged) ----------------
__device__ __forceinline__ void block_reduce2(float& s, float& ss, float* red, int tid, int nthreads) {
    #pragma unroll
    for (int off = 32; off > 0; off >>= 1) {
        s  += __shfl_down(s, off);
        ss += __shfl_down(ss, off);
    }
    int wid = tid >> 6, nw = nthreads >> 6;
    if ((tid & 63) == 0) { red[wid*2] = s; red[wid*2+1] = ss; }
    __syncthreads();
    if (tid == 0) {
        float S = 0.f, SS = 0.f;
        for (int i = 0; i < nw; i++) { S += red[i*2]; SS += red[i*2+1]; }
        red[0] = S; red[1] = SS;
    }
    __syncthreads();
    s = red[0]; ss = red[1];
}

__global__ __launch_bounds__(256) void k_stage0(const float* __restrict__ posi,
                                                const float* __restrict__ w0,
                                                const float* __restrict__ g0,
                                                const float* __restrict__ b0,
                                                float* __restrict__ a_out) {
    __shared__ __align__(16) float ppad[POSI][16][16];
    __shared__ __align__(16) float t[INTER * P];
    __shared__ float red[64];
    int tid = threadIdx.x;
    for (int i = tid; i < POSI * 256; i += 256) {
        int c = i >> 8, r = i & 255, ly = r >> 4, lx = r & 15;
        float v = 0.f;
        if (ly >= 1 && ly <= HP && lx >= 1 && lx <= WP) v = posi[c*P + (ly-1)*WP + (lx-1)];
        ppad[c][ly][lx] = v;
    }
    __syncthreads();
    float s = 0.f, ss = 0.f;
    for (int idx = tid; idx < INTER * P; idx += 256) {
        int c = idx / P, p = idx - c*P, y = p / WP, x = p - (p/WP)*WP;
        float acc = 0.f;
        #pragma unroll
        for (int ci = 0; ci < POSI; ci++)
            #pragma unroll
            for (int dy = 0; dy < 3; dy++)
                #pragma unroll
                for (int dx = 0; dx < 3; dx++)
                    acc += w0[((c*POSI + ci)*3 + dy)*3 + dx] * ppad[ci][y+dy][x+dx];
        t[idx] = acc; s += acc; ss += acc*acc;
    }
    block_reduce2(s, ss, red, tid, 256);
    float mu = s / (float)(INTER*P);
    float var = ss / (float)(INTER*P) - mu*mu;
    float rstd = rsqrtf(var + EPSLN);
    for (int idx = tid; idx < INTER * P; idx += 256) {
        float v = (t[idx] - mu) * rstd * g0[idx] + b0[idx];
        a_out[idx] = v > 0.f ? v : 0.f;
    }
}

__global__ __launch_bounds__(256) void k_conv64(const float* __restrict__ a,
                                                const float* __restrict__ w,
                                                float* __restrict__ v) {
    __shared__ __align__(16) float as[INTER][16][16];
    int tid = threadIdx.x;
    for (int i = tid; i < INTER * 256; i += 256) {
        int c = i >> 8, r = i & 255, ly = r >> 4, lx = r & 15;
        float val = 0.f;
        if (ly >= 1 && ly <= HP && lx >= 1 && lx <= WP) val = a[c*P + (ly-1)*WP + (lx-1)];
        as[c][ly][lx] = val;
    }
    __syncthreads();
    int idx = blockIdx.x * 256 + tid;
    int c = idx / P, p = idx - c*P, y = p / WP, x = p - (p/WP)*WP;
    float acc = 0.f;
    for (int ci = 0; ci < INTER; ci++) {
        const float* wr = w + (c*INTER + ci)*9;
        acc += wr[0]*as[ci][y  ][x] + wr[1]*as[ci][y  ][x+1] + wr[2]*as[ci][y  ][x+2]
             + wr[3]*as[ci][y+1][x] + wr[4]*as[ci][y+1][x+1] + wr[5]*as[ci][y+1][x+2]
             + wr[6]*as[ci][y+2][x] + wr[7]*as[ci][y+2][x+1] + wr[8]*as[ci][y+2][x+2];
    }
    v[idx] = acc;
}

__global__ __launch_bounds__(1024) void k_lnrelu(const float* __restrict__ v,
                                                 const float* __restrict__ g,
                                                 const float* __restrict__ b,
                                                 float* __restrict__ a) {
    __shared__ float red[64];
    int tid = threadIdx.x;
    float s = 0.f, ss = 0.f;
    float vals[13];
    int cnt = 0;
    for (int idx = tid; idx < INTER * P; idx += 1024) {
        float x = v[idx]; vals[cnt++] = x; s += x; ss += x*x;
    }
    block_reduce2(s, ss, red, tid, 1024);
    float mu = s / (float)(INTER*P);
    float var = ss / (float)(INTER*P) - mu*mu;
    float rstd = rsqrtf(var + EPSLN);
    cnt = 0;
    for (int idx = tid; idx < INTER * P; idx += 1024) {
        float x = (vals[cnt++] - mu) * rstd * g[idx] + b[idx];
        a[idx] = x > 0.f ? x : 0.f;
    }
}

__global__ void k_im2col(const float* __restrict__ a, unsigned short* __restrict__ imc) {
    int idx = blockIdx.x * 256 + threadIdx.x;
    if (idx >= P * KIM) return;
    int p = idx / KIM, q = idx - p * KIM;
    int ci = q / 9, k = q - ci * 9;
    int y = p / WP + k / 3 - 1, x = p % WP + k % 3 - 1;
    float v = 0.f;
    if (y >= 0 && y < HP && x >= 0 && x < WP) v = a[ci * P + y * WP + x];
    imc[idx] = f2bf(v);
}

// final conv as LDS-staged tiled MFMA GEMM, k-major M: wgtT[p][k][ch] written coalesced.
// block = 64 m x 196 p, 4 waves; As/Bs unioned with ot (28.2 KB LDS)
__global__ __launch_bounds__(256) void k_gemm_wf(const unsigned short* __restrict__ wfb,
                                                 const unsigned short* __restrict__ imc,
                                                 unsigned short* __restrict__ wgtT) {
    __shared__ __align__(16) unsigned short buf[P * 72];     // 28.2 KB
    unsigned short* As = buf;                                // 64*32 = 2048
    unsigned short* Bs = buf + 2048;                         // 208*32 = 6656
    unsigned short* ot = buf;                                // reused after K-loop
    int tid = threadIdx.x;
    int w = tid >> 6, lane = tid & 63, quad = lane >> 4, c16 = lane & 15;
    int m0 = blockIdx.x * 64;                                // 198 blocks
    for (int i = tid; i < 48; i += 256)                      // zero Bs pad rows 196..207
        *(short8*)(Bs + 196 * 32 + i * 8) = (short8)0;
    f32x4 acc[13];
    #pragma unroll
    for (int f = 0; f < 13; f++) acc[f] = (f32x4)0.f;

    for (int kc = 0; kc < 18; ++kc) {
        int k0 = kc * 32;
        if (kc) __syncthreads();
        {                                                    // A: 64 rows x 4 pieces
            int i = tid;
            int r = i >> 2, s = i & 3, q = (s - (r >> 1)) & 3;
            gl2lds16(wfb + (size_t)(m0 + r) * KIM + k0 + q * 8, As + (i & ~63) * 8);
        }
        for (int i = tid; i < 784; i += 256) {               // B: 196 rows x 4 pieces
            int r = i >> 2, s = i & 3, q = (s - (r >> 1)) & 3;
            gl2lds16(imc + (size_t)r * KIM + k0 + q * 8, Bs + (i & ~63) * 8);
        }
        __syncthreads();
        short8 af = fragld(As, w * 16 + c16, quad);
        #pragma unroll
        for (int f = 0; f < 13; f++) {
            short8 bf = fragld(Bs, f * 16 + c16, quad);
            acc[f] = __builtin_amdgcn_mfma_f32_16x16x32_bf16(af, bf, acc[f], 0, 0, 0);
        }
    }
    __syncthreads();
    #pragma unroll
    for (int f = 0; f < 13; f++) {
        int p = f * 16 + c16;
        if (p < P) {
            short4v sv;
            sv[0] = (short)f2bf(acc[f][0]);
            sv[1] = (short)f2bf(acc[f][1]);
            sv[2] = (short)f2bf(acc[f][2]);
            sv[3] = (short)f2bf(acc[f][3]);
            *(short4v*)(ot + p * 72 + w * 16 + quad * 4) = sv;
        }
    }
    __syncthreads();
    int kk = m0 / MW, ch0 = m0 - kk * MW;                    // tile never crosses k-plane
    int nvalid = CHN - ch0; if (nvalid > 64) nvalid = 64;    // 64 or 16
    for (int p = tid; p < P; p += 256) {
        const short8* src = (const short8*)(ot + p * 72);
        unsigned short* dst = wgtT + ((size_t)p * 9 + kk) * CHN + ch0;
        #pragma unroll
        for (int j = 0; j < 8; j++)
            if (j * 8 < nvalid) *(short8*)(dst + j * 8) = src[j];
    }
}

// ---------------- tiled MFMA GEMM 1: h1t[n][m] = sum_k Wbin[m][k] Xt[n][k] ----------------
__global__ __launch_bounds__(256) void k_gemm_in(const unsigned short* __restrict__ A,
                                                 const unsigned short* __restrict__ B,
                                                 unsigned short* __restrict__ C) {
    __shared__ __align__(16) unsigned short As[128 * 32];
    __shared__ __align__(16) unsigned short Bs[128 * 32];
    int tid = threadIdx.x;
    int w = tid >> 6, lane = tid & 63, quad = lane >> 4, c16 = lane & 15;
    int m0 = blockIdx.x * 128, n0 = blockIdx.y * 128;
    int wm = (w & 1) * 64, wn = (w >> 1) * 64;
    f32x4 acc[4][4];
    #pragma unroll
    for (int i = 0; i < 4; i++)
        #pragma unroll
        for (int j = 0; j < 4; j++) acc[i][j] = (f32x4)0.f;

    for (int kc = 0; kc < 8; ++kc) {
        int k0 = kc * 32;
        if (kc) __syncthreads();
        #pragma unroll
        for (int i = tid; i < 512; i += 256) {
            int r = i >> 2, s = i & 3, q = (s - (r >> 1)) & 3;
            gl2lds16(A + (size_t)(m0 + r) * DIMC + k0 + q * 8, As + (i & ~63) * 8);
        }
        #pragma unroll
        for (int i = tid; i < 512; i += 256) {
            int r = i >> 2, s = i & 3, q = (s - (r >> 1)) & 3;
            gl2lds16(B + (size_t)(n0 + r) * DIMC + k0 + q * 8, Bs + (i & ~63) * 8);
        }
        __syncthreads();
        short8 af[4], bfr[4];
        #pragma unroll
        for (int i = 0; i < 4; i++) af[i] = fragld(As, wm + i * 16 + c16, quad);
        #pragma unroll
        for (int j = 0; j < 4; j++) bfr[j] = fragld(Bs, wn + j * 16 + c16, quad);
        #pragma unroll
        for (int i = 0; i < 4; i++)
            #pragma unroll
            for (int j = 0; j < 4; j++)
                acc[i][j] = __builtin_amdgcn_mfma_f32_16x16x32_bf16(af[i], bfr[j], acc[i][j], 0, 0, 0);
    }
    #pragma unroll
    for (int j = 0; j < 4; j++) {
        int n = n0 + wn + j * 16 + c16;
        unsigned short* dst = C + (size_t)n * CHN;
        #pragma unroll
        for (int i = 0; i < 4; i++) {
            int m = m0 + wm + i * 16 + quad * 4;
            if (m < CHN) {
                short4v sv;
                sv[0] = (short)f2bf(acc[i][j][0]);
                sv[1] = (short)f2bf(acc[i][j][1]);
                sv[2] = (short)f2bf(acc[i][j][2]);
                sv[3] = (short)f2bf(acc[i][j][3]);
                *(short4v*)(dst + m) = sv;
            }
        }
    }
}

// ---------------- fused tvconv + gelu-gate: XCD-affinity swizzled grid ----------------
// 1D grid 800: xcd = id&7 gets contiguous 25-pixel strip; bg waves per strip.
__global__ __launch_bounds__(256) void k_tvg(const unsigned short* __restrict__ h1t,
                                             const unsigned short* __restrict__ wgtT,
                                             unsigned short* __restrict__ hgt) {
    __shared__ __align__(16) unsigned short wl[9 * CHN];   // 24480 B, [k][CHN]
    int id = blockIdx.x;
    int xcd = id & 7, q = id >> 3;
    int p = xcd * 25 + (q % 25);
    int bg = q / 25;
    if (p >= P) return;
    int b0 = bg * 16, tid = threadIdx.x;
    const unsigned short* wrow = wgtT + (size_t)p * 9 * CHN;
    for (int i = tid * 8; i < 9 * CHN; i += 256 * 8)
        *(short8*)(wl + i) = *(const short8*)(wrow + i);
    int y = p / WP, x = p - (p / WP) * WP;
    int pn[9]; bool pv[9];
    #pragma unroll
    for (int k = 0; k < 9; k++) {
        int yy = y + k / 3 - 1, xx = x + (k % 3) - 1;
        pv[k] = (yy >= 0 && yy < HP && xx >= 0 && xx < WP);
        pn[k] = pv[k] ? yy * WP + xx : 0;
    }
    __syncthreads();
    for (int j = tid; j < 16 * 85; j += 256) {
        int bl = j / 85, c = (j - bl * 85) * 8;
        int b = b0 + bl;
        const unsigned short* hb = h1t + (size_t)b * P * CHN;
        float s1[8], s2[8];
        #pragma unroll
        for (int e = 0; e < 8; e++) { s1[e] = 0.f; s2[e] = 0.f; }
        #pragma unroll
        for (int k = 0; k < 9; k++) {
            if (!pv[k]) continue;
            const unsigned short* hr = hb + (size_t)pn[k] * CHN + c;
            short8 h1v = *(const short8*)hr;
            short8 h2v = *(const short8*)(hr + HID);
            short8 w1v = *(const short8*)(wl + k * CHN + c);
            short8 w2v = *(const short8*)(wl + k * CHN + HID + c);
            #pragma unroll
            for (int e = 0; e < 8; e++) {
                s1[e] += bf2f((unsigned short)w1v[e]) * bf2f((unsigned short)h1v[e]);
                s2[e] += bf2f((unsigned short)w2v[e]) * bf2f((unsigned short)h2v[e]);
            }
        }
        short8 o;
        #pragma unroll
        for (int e = 0; e < 8; e++) {
            float gl = 0.5f * s1[e] * (1.f + erff(s1[e] * 0.70710678118654752f));
            o[e] = (short)f2bf(gl * s2[e]);
        }
        *(short8*)(hgt + ((size_t)b * P + p) * KPAD + c) = o;
    }
    if (tid < 48) {
        int bl = tid / 3, z = (tid - bl * 3) * 8;
        *(short8*)(hgt + ((size_t)(b0 + bl) * P + p) * KPAD + HID + z) = (short8)0;
    }
}

// ---------------- tiled MFMA GEMM 2: out[m][n] = sum_k Wbout[m][k] hgt[n][k] ----------------
__global__ __launch_bounds__(256) void k_gemm_out(const unsigned short* __restrict__ A,
                                                  const unsigned short* __restrict__ B,
                                                  float* __restrict__ out) {
    __shared__ __align__(16) unsigned short As[64 * 32];
    __shared__ __align__(16) unsigned short Bs[128 * 32];
    int tid = threadIdx.x;
    int w = tid >> 6, lane = tid & 63, quad = lane >> 4, c16 = lane & 15;
    int m0 = blockIdx.x * 64, n0 = blockIdx.y * 128;
    int wm = (w & 1) * 32, wn = (w >> 1) * 64;
    f32x4 acc[2][4];
    #pragma unroll
    for (int i = 0; i < 2; i++)
        #pragma unroll
        for (int j = 0; j < 4; j++) acc[i][j] = (f32x4)0.f;

    for (int kc = 0; kc < 22; ++kc) {
        int k0 = kc * 32;
        if (kc) __syncthreads();
        {
            int i = tid;
            int r = i >> 2, s = i & 3, q = (s - (r >> 1)) & 3;
            gl2lds16(A + (size_t)(m0 + r) * KPAD + k0 + q * 8, As + (i & ~63) * 8);
        }
        #pragma unroll
        for (int i = tid; i < 512; i += 256) {
            int r = i >> 2, s = i & 3, q = (s - (r >> 1)) & 3;
            gl2lds16(B + (size_t)(n0 + r) * KPAD + k0 + q * 8, Bs + (i & ~63) * 8);
        }
        __syncthreads();
        short8 af[2], bfr[4];
        #pragma unroll
        for (int i = 0; i < 2; i++) af[i] = fragld(As, wm + i * 16 + c16, quad);
        #pragma unroll
        for (int j = 0; j < 4; j++) bfr[j] = fragld(Bs, wn + j * 16 + c16, quad);
        #pragma unroll
        for (int i = 0; i < 2; i++)
            #pragma unroll
            for (int j = 0; j < 4; j++)
                acc[i][j] = __builtin_amdgcn_mfma_f32_16x16x32_bf16(af[i], bfr[j], acc[i][j], 0, 0, 0);
    }
    #pragma unroll
    for (int j = 0; j < 4; j++) {
        int n = n0 + wn + j * 16 + c16;
        int b = n / P, pp = n - b * P;
        #pragma unroll
        for (int i = 0; i < 2; i++) {
            int m = m0 + wm + i * 16 + quad * 4;
            #pragma unroll
            for (int r = 0; r < 4; r++)
                out[((size_t)b * DIMC + m + r) * P + pp] = acc[i][j][r];
        }
    }
}

extern "C" void kernel_launch(void* const* d_in, const int* in_sizes, int n_in,
                              void* d_out, int out_size, void* d_ws, size_t ws_size,
                              hipStream_t stream) {
    (void)in_sizes; (void)n_in; (void)out_size; (void)ws_size;
    const float* x     = (const float*)d_in[0];
    const float* W_in  = (const float*)d_in[1];
    const float* posi  = (const float*)d_in[2];
    const float* w0    = (const float*)d_in[3];
    const float* g0    = (const float*)d_in[4];
    const float* b0    = (const float*)d_in[5];
    const float* w1    = (const float*)d_in[6];
    const float* g1    = (const float*)d_in[7];
    const float* b1    = (const float*)d_in[8];
    const float* w2    = (const float*)d_in[9];
    const float* g2    = (const float*)d_in[10];
    const float* b2    = (const float*)d_in[11];
    const float* wf    = (const float*)d_in[12];
    const float* W_out = (const float*)d_in[13];
    float* out = (float*)d_out;
    char* ws = (char*)d_ws;

    unsigned short* Wbin  = (unsigned short*)(ws + OFS_WBIN);
    unsigned short* Wbout = (unsigned short*)(ws + OFS_WBOUT);
    unsigned short* Xt    = (unsigned short*)(ws + OFS_XT);
    float*          a_buf = (float*)(ws + OFS_ABUF);
    float*          v_buf = (float*)(ws + OFS_VBUF);
    unsigned short* wgtT  = (unsigned short*)(ws + OFS_WGTT);
    unsigned short* h1t   = (unsigned short*)(ws + OFS_H1T);
    unsigned short* hgt   = (unsigned short*)(ws + OFS_HGT);
    unsigned short* wfb   = (unsigned short*)(ws + OFS_WFB);
    unsigned short* imc   = (unsigned short*)(ws + OFS_IMC);

    // casts / transposes
    k_cast_win <<<(MPADIN*DIMC + 255)/256, 256, 0, stream>>>(W_in, Wbin);
    k_cast_wout<<<(DIMC*KPAD + 255)/256, 256, 0, stream>>>(W_out, Wbout);
    k_cast_wf  <<<(MTOT*KIM/4 + 255)/256, 256, 0, stream>>>(wf, wfb);
    k_xt       <<<dim3(DIMC/32, BATCH), 256, 0, stream>>>(x, Xt);

    // weight-generator network
    k_stage0<<<1, 256, 0, stream>>>(posi, w0, g0, b0, a_buf);
    k_conv64<<<49, 256, 0, stream>>>(a_buf, w1, v_buf);
    k_lnrelu<<<1, 1024, 0, stream>>>(v_buf, g1, b1, a_buf);
    k_conv64<<<49, 256, 0, stream>>>(a_buf, w2, v_buf);
    k_lnrelu<<<1, 1024, 0, stream>>>(v_buf, g2, b2, a_buf);
    k_im2col<<<(P*KIM + 255)/256, 256, 0, stream>>>(a_buf, imc);
    k_gemm_wf<<<MTOT/64, 256, 0, stream>>>(wfb, imc, wgtT);

    // main path (tiled MFMA)
    k_gemm_in <<<dim3(MPADIN/128, (BATCH*P)/128), 256, 0, stream>>>(Wbin, Xt, h1t);
    k_tvg     <<<800, 256, 0, stream>>>(h1t, wgtT, hgt);
    k_gemm_out<<<dim3(DIMC/64, (BATCH*P)/128), 256, 0, stream>>>(Wbout, hgt, out);
}

// Round 8
// 304.195 us; speedup vs baseline: 3.2513x; 1.0558x over previous
//
#include <hip/hip_runtime.h>
#include <math.h>

// ---- problem constants ----
#define DIMC   256
#define HID    680
#define CHN    1360
#define HP     14
#define WP     14
#define P      196
#define POSI   4
#define INTER  64
#define BATCH  64
#define KPAD   704          // 680 padded to 22*32
#define OUTCH  12240        // CHN*9
#define MW     1408         // per-k-plane channel pad
#define MTOT   12672        // 9*MW
#define KIM    576          // INTER*9
#define MPADIN 1408         // 1360 padded to 11*128
#define EPSLN  1e-5f

typedef __attribute__((ext_vector_type(8))) short short8;
typedef __attribute__((ext_vector_type(4))) short short4v;
typedef __attribute__((ext_vector_type(4))) float f32x4;

// ---- workspace layout (bytes) ----
#define OFS_WBIN  0u                  // 1408*256*2   = 720896
#define OFS_WBOUT 720896u             // 256*704*2    = 360448
#define OFS_XT    1081344u            // 64*196*256*2 = 6422528
#define OFS_ABUF  7503872u            // 12544*4
#define OFS_VBUF  7554048u            // 12544*4
#define OFS_WGTT  7604224u            // 196*9*1360*2 = 4798080  ([p][k][ch])
#define OFS_H1T   12402304u           // 64*196*1360*2 = 34127872
#define OFS_HGT   46530176u           // 64*196*704*2  = 17661952
#define OFS_IMC   64192128u           // 196*576*2     = 225792   (end ~64.4MB)

__device__ __forceinline__ unsigned short f2bf(float f) {
    union { float f; unsigned u; } v; v.f = f;
    unsigned u = v.u;
    return (unsigned short)((u + 0x7FFFu + ((u >> 16) & 1u)) >> 16);   // RNE
}
__device__ __forceinline__ float bf2f(unsigned short h) {
    union { unsigned u; float f; } v; v.u = ((unsigned)h) << 16; return v.f;
}

// async 16B global->LDS (wave-uniform LDS base + lane*16; global src may be per-lane)
__device__ __forceinline__ void gl2lds16(const unsigned short* g, unsigned short* l) {
    __builtin_amdgcn_global_load_lds(
        (const __attribute__((address_space(1))) unsigned int*)g,
        (__attribute__((address_space(3))) unsigned int*)l, 16, 0, 0);
}
__device__ __forceinline__ void gl2lds16f(const float* g, float* l) {
    __builtin_amdgcn_global_load_lds(
        (const __attribute__((address_space(1))) unsigned int*)g,
        (__attribute__((address_space(3))) unsigned int*)l, 16, 0, 0);
}
// BK=32 tile: row stride 32, 4 slots, rotate by row>>1
__device__ __forceinline__ short8 fragld(const unsigned short* S, int row, int quad) {
    int slot = ((row >> 1) + quad) & 3;
    return *(const short8*)(S + row * 32 + slot * 8);
}
// BK=64 tile: row stride 64, 8 slots of 16B, logical piece lp in 0..7
__device__ __forceinline__ short8 fragld64(const unsigned short* S, int row, int lp) {
    int slot = ((row >> 1) + lp) & 7;
    return *(const short8*)(S + row * 64 + slot * 8);
}
// f32 BK=32 tile (row stride 32 floats, 8 slots of 4 floats): bf16 fragment for quad
__device__ __forceinline__ short8 fragldf(const float* S, int row, int quad) {
    int lp0 = quad * 2;
    int s0 = ((row >> 1) + lp0) & 7, s1 = ((row >> 1) + lp0 + 1) & 7;
    float4 a = *(const float4*)(S + row * 32 + s0 * 4);
    float4 b = *(const float4*)(S + row * 32 + s1 * 4);
    short8 r;
    r[0] = (short)f2bf(a.x); r[1] = (short)f2bf(a.y);
    r[2] = (short)f2bf(a.z); r[3] = (short)f2bf(a.w);
    r[4] = (short)f2bf(b.x); r[5] = (short)f2bf(b.y);
    r[6] = (short)f2bf(b.z); r[7] = (short)f2bf(b.w);
    return r;
}

// ---------------- merged weight casts ----------------
#define NWIN  (MPADIN*DIMC)
#define NWOUT (DIMC*KPAD)
__global__ void k_casts(const float* __restrict__ Win, const float* __restrict__ Wout,
                        unsigned short* __restrict__ Wbin, unsigned short* __restrict__ Wbout) {
    int i = blockIdx.x * 256 + threadIdx.x;
    if (i < NWIN) {
        Wbin[i] = (i < CHN * DIMC) ? f2bf(Win[i]) : (unsigned short)0;
    } else if (i < NWIN + NWOUT) {
        int j = i - NWIN;
        int o = j / KPAD, k = j - o * KPAD;
        Wbout[j] = f2bf(k < HID ? Wout[o * HID + k] : 0.f);
    }
}
// x [64][256][196] f32 -> Xt [64][196][256] bf16
__global__ __launch_bounds__(256) void k_xt(const float* __restrict__ x,
                                            unsigned short* __restrict__ Xt) {
    __shared__ float xs[32][197];
    int b = blockIdx.y, c0 = blockIdx.x * 32, tid = threadIdx.x;
    for (int i = tid; i < 32 * P; i += 256) {
        int ci = i / P, pp = i - ci * P;
        xs[ci][pp] = x[((size_t)b * DIMC + c0 + ci) * P + pp];
    }
    __syncthreads();
    for (int j = tid; j < P * 32; j += 256) {
        int ci = j & 31, pp = j >> 5;
        Xt[((size_t)b * P + pp) * DIMC + c0 + ci] = f2bf(xs[ci][pp]);
    }
}

// ---------------- weight-generator net head ----------------
__device__ __forceinline__ void block_reduce2(float& s, float& ss, float* red, int tid, int nthreads) {
    #pragma unroll
    for (int off = 32; off > 0; off >>= 1) {
        s  += __shfl_down(s, off);
        ss += __shfl_down(ss, off);
    }
    int wid = tid >> 6, nw = nthreads >> 6;
    if ((tid & 63) == 0) { red[wid*2] = s; red[wid*2+1] = ss; }
    __syncthreads();
    if (tid == 0) {
        float S = 0.f, SS = 0.f;
        for (int i = 0; i < nw; i++) { S += red[i*2]; SS += red[i*2+1]; }
        red[0] = S; red[1] = SS;
    }
    __syncthreads();
    s = red[0]; ss = red[1];
}

__global__ __launch_bounds__(256) void k_stage0(const float* __restrict__ posi,
                                                const float* __restrict__ w0,
                                                const float* __restrict__ g0,
                                                const float* __restrict__ b0,
                                                float* __restrict__ a_out) {
    __shared__ __align__(16) float ppad[POSI][16][16];
    __shared__ __align__(16) float t[INTER * P];
    __shared__ float red[64];
    int tid = threadIdx.x;
    for (int i = tid; i < POSI * 256; i += 256) {
        int c = i >> 8, r = i & 255, ly = r >> 4, lx = r & 15;
        float v = 0.f;
        if (ly >= 1 && ly <= HP && lx >= 1 && lx <= WP) v = posi[c*P + (ly-1)*WP + (lx-1)];
        ppad[c][ly][lx] = v;
    }
    __syncthreads();
    float s = 0.f, ss = 0.f;
    for (int idx = tid; idx < INTER * P; idx += 256) {
        int c = idx / P, p = idx - c*P, y = p / WP, x = p - (p/WP)*WP;
        float acc = 0.f;
        #pragma unroll
        for (int ci = 0; ci < POSI; ci++)
            #pragma unroll
            for (int dy = 0; dy < 3; dy++)
                #pragma unroll
                for (int dx = 0; dx < 3; dx++)
                    acc += w0[((c*POSI + ci)*3 + dy)*3 + dx] * ppad[ci][y+dy][x+dx];
        t[idx] = acc; s += acc; ss += acc*acc;
    }
    block_reduce2(s, ss, red, tid, 256);
    float mu = s / (float)(INTER*P);
    float var = ss / (float)(INTER*P) - mu*mu;
    float rstd = rsqrtf(var + EPSLN);
    for (int idx = tid; idx < INTER * P; idx += 256) {
        float v = (t[idx] - mu) * rstd * g0[idx] + b0[idx];
        a_out[idx] = v > 0.f ? v : 0.f;
    }
}

__global__ __launch_bounds__(256) void k_conv64(const float* __restrict__ a,
                                                const float* __restrict__ w,
                                                float* __restrict__ v) {
    __shared__ __align__(16) float as[INTER][16][16];
    int tid = threadIdx.x;
    for (int i = tid; i < INTER * 256; i += 256) {
        int c = i >> 8, r = i & 255, ly = r >> 4, lx = r & 15;
        float val = 0.f;
        if (ly >= 1 && ly <= HP && lx >= 1 && lx <= WP) val = a[c*P + (ly-1)*WP + (lx-1)];
        as[c][ly][lx] = val;
    }
    __syncthreads();
    int idx = blockIdx.x * 256 + tid;
    int c = idx / P, p = idx - c*P, y = p / WP, x = p - (p/WP)*WP;
    float acc = 0.f;
    for (int ci = 0; ci < INTER; ci++) {
        const float* wr = w + (c*INTER + ci)*9;
        acc += wr[0]*as[ci][y  ][x] + wr[1]*as[ci][y  ][x+1] + wr[2]*as[ci][y  ][x+2]
             + wr[3]*as[ci][y+1][x] + wr[4]*as[ci][y+1][x+1] + wr[5]*as[ci][y+1][x+2]
             + wr[6]*as[ci][y+2][x] + wr[7]*as[ci][y+2][x+1] + wr[8]*as[ci][y+2][x+2];
    }
    v[idx] = acc;
}

__global__ __launch_bounds__(1024) void k_lnrelu(const float* __restrict__ v,
                                                 const float* __restrict__ g,
                                                 const float* __restrict__ b,
                                                 float* __restrict__ a) {
    __shared__ float red[64];
    int tid = threadIdx.x;
    float s = 0.f, ss = 0.f;
    float vals[13];
    int cnt = 0;
    for (int idx = tid; idx < INTER * P; idx += 1024) {
        float x = v[idx]; vals[cnt++] = x; s += x; ss += x*x;
    }
    block_reduce2(s, ss, red, tid, 1024);
    float mu = s / (float)(INTER*P);
    float var = ss / (float)(INTER*P) - mu*mu;
    float rstd = rsqrtf(var + EPSLN);
    cnt = 0;
    for (int idx = tid; idx < INTER * P; idx += 1024) {
        float x = (vals[cnt++] - mu) * rstd * g[idx] + b[idx];
        a[idx] = x > 0.f ? x : 0.f;
    }
}

__global__ void k_im2col(const float* __restrict__ a, unsigned short* __restrict__ imc) {
    int idx = blockIdx.x * 256 + threadIdx.x;
    if (idx >= P * KIM) return;
    int p = idx / KIM, q = idx - p * KIM;
    int ci = q / 9, k = q - ci * 9;
    int y = p / WP + k / 3 - 1, x = p % WP + k % 3 - 1;
    float v = 0.f;
    if (y >= 0 && y < HP && x >= 0 && x < WP) v = a[ci * P + y * WP + x];
    imc[idx] = f2bf(v);
}

// final conv as tiled MFMA GEMM; A staged DIRECTLY from wf (f32) with k-major row map.
// block = 64 m x 196 p, 4 waves, 18 K-chunks of 32
__global__ __launch_bounds__(256) void k_gemm_wf(const float* __restrict__ wf,
                                                 const unsigned short* __restrict__ imc,
                                                 unsigned short* __restrict__ wgtT) {
    __shared__ __align__(16) unsigned short buf[P * 72];     // 28.2 KB
    float*          Asf = (float*)buf;                       // 64*32 f32 = 8 KB
    unsigned short* Bs  = buf + 4096;                        // 208*32 bf16 = 13 KB
    unsigned short* ot  = buf;                               // reused after K-loop
    int tid = threadIdx.x;
    int w = tid >> 6, lane = tid & 63, quad = lane >> 4, c16 = lane & 15;
    int m0 = blockIdx.x * 64;                                // 198 blocks
    int kk = m0 / MW, ch0 = m0 - kk * MW;                    // tile within one k-plane
    for (int i = tid; i < 48; i += 256)                      // zero Bs pad rows 196..207
        *(short8*)(Bs + 196 * 32 + i * 8) = (short8)0;
    f32x4 acc[13];
    #pragma unroll
    for (int f = 0; f < 13; f++) acc[f] = (f32x4)0.f;

    for (int kc = 0; kc < 18; ++kc) {
        int k0 = kc * 32;
        if (kc) __syncthreads();
        #pragma unroll
        for (int i = tid; i < 512; i += 256) {               // A: 64 rows x 8 f32-pieces
            int r = i >> 3, s = i & 7, q = (s - (r >> 1)) & 7;
            int ch = ch0 + r; if (ch >= CHN) ch = CHN - 1;   // clamp; discarded at store
            gl2lds16f(wf + (size_t)(ch * 9 + kk) * KIM + k0 + q * 4, Asf + (i & ~63) * 4);
        }
        for (int i = tid; i < 784; i += 256) {               // B: 196 rows x 4 pieces
            int r = i >> 2, s = i & 3, q = (s - (r >> 1)) & 3;
            gl2lds16(imc + (size_t)r * KIM + k0 + q * 8, Bs + (i & ~63) * 8);
        }
        __syncthreads();
        short8 af = fragldf(Asf, w * 16 + c16, quad);
        #pragma unroll
        for (int f = 0; f < 13; f++) {
            short8 bf = fragld(Bs, f * 16 + c16, quad);
            acc[f] = __builtin_amdgcn_mfma_f32_16x16x32_bf16(af, bf, acc[f], 0, 0, 0);
        }
    }
    __syncthreads();
    #pragma unroll
    for (int f = 0; f < 13; f++) {
        int p = f * 16 + c16;
        if (p < P) {
            short4v sv;
            sv[0] = (short)f2bf(acc[f][0]);
            sv[1] = (short)f2bf(acc[f][1]);
            sv[2] = (short)f2bf(acc[f][2]);
            sv[3] = (short)f2bf(acc[f][3]);
            *(short4v*)(ot + p * 72 + w * 16 + quad * 4) = sv;
        }
    }
    __syncthreads();
    int nvalid = CHN - ch0; if (nvalid > 64) nvalid = 64;
    for (int p = tid; p < P; p += 256) {
        const short8* src = (const short8*)(ot + p * 72);
        unsigned short* dst = wgtT + ((size_t)p * 9 + kk) * CHN + ch0;
        #pragma unroll
        for (int j = 0; j < 8; j++)
            if (j * 8 < nvalid) *(short8*)(dst + j * 8) = src[j];
    }
}

// ---------------- tiled MFMA GEMM 1 (BK=64): h1t[n][m] = sum_k Wbin[m][k] Xt[n][k] --------
__global__ __launch_bounds__(256) void k_gemm_in(const unsigned short* __restrict__ A,
                                                 const unsigned short* __restrict__ B,
                                                 unsigned short* __restrict__ C) {
    __shared__ __align__(16) unsigned short As[128 * 64];    // 16 KB
    __shared__ __align__(16) unsigned short Bs[128 * 64];    // 16 KB
    int tid = threadIdx.x;
    int w = tid >> 6, lane = tid & 63, quad = lane >> 4, c16 = lane & 15;
    int m0 = blockIdx.x * 128, n0 = blockIdx.y * 128;
    int wm = (w & 1) * 64, wn = (w >> 1) * 64;
    f32x4 acc[4][4];
    #pragma unroll
    for (int i = 0; i < 4; i++)
        #pragma unroll
        for (int j = 0; j < 4; j++) acc[i][j] = (f32x4)0.f;

    for (int kc = 0; kc < 4; ++kc) {                         // K=256, chunks of 64
        int k0 = kc * 64;
        if (kc) __syncthreads();
        #pragma unroll
        for (int i = tid; i < 1024; i += 256) {              // A: 128 rows x 8 pieces
            int r = i >> 3, s = i & 7, q = (s - (r >> 1)) & 7;
            gl2lds16(A + (size_t)(m0 + r) * DIMC + k0 + q * 8, As + (i & ~63) * 8);
        }
        #pragma unroll
        for (int i = tid; i < 1024; i += 256) {              // B: 128 rows x 8 pieces
            int r = i >> 3, s = i & 7, q = (s - (r >> 1)) & 7;
            gl2lds16(B + (size_t)(n0 + r) * DIMC + k0 + q * 8, Bs + (i & ~63) * 8);
        }
        __syncthreads();
        #pragma unroll
        for (int ks = 0; ks < 2; ++ks) {
            short8 af[4], bfr[4];
            #pragma unroll
            for (int i = 0; i < 4; i++) af[i] = fragld64(As, wm + i * 16 + c16, ks * 4 + quad);
            #pragma unroll
            for (int j = 0; j < 4; j++) bfr[j] = fragld64(Bs, wn + j * 16 + c16, ks * 4 + quad);
            #pragma unroll
            for (int i = 0; i < 4; i++)
                #pragma unroll
                for (int j = 0; j < 4; j++)
                    acc[i][j] = __builtin_amdgcn_mfma_f32_16x16x32_bf16(af[i], bfr[j], acc[i][j], 0, 0, 0);
        }
    }
    #pragma unroll
    for (int j = 0; j < 4; j++) {
        int n = n0 + wn + j * 16 + c16;
        unsigned short* dst = C + (size_t)n * CHN;
        #pragma unroll
        for (int i = 0; i < 4; i++) {
            int m = m0 + wm + i * 16 + quad * 4;
            if (m < CHN) {
                short4v sv;
                sv[0] = (short)f2bf(acc[i][j][0]);
                sv[1] = (short)f2bf(acc[i][j][1]);
                sv[2] = (short)f2bf(acc[i][j][2]);
                sv[3] = (short)f2bf(acc[i][j][3]);
                *(short4v*)(dst + m) = sv;
            }
        }
    }
}

// ---------------- fused tvconv + gelu-gate: XCD-affinity swizzled grid ----------------
__global__ __launch_bounds__(256) void k_tvg(const unsigned short* __restrict__ h1t,
                                             const unsigned short* __restrict__ wgtT,
                                             unsigned short* __restrict__ hgt) {
    __shared__ __align__(16) unsigned short wl[9 * CHN];   // 24480 B, [k][CHN]
    int id = blockIdx.x;
    int xcd = id & 7, q = id >> 3;
    int p = xcd * 25 + (q % 25);
    int bg = q / 25;
    if (p >= P) return;
    int b0 = bg * 16, tid = threadIdx.x;
    const unsigned short* wrow = wgtT + (size_t)p * 9 * CHN;
    for (int i = tid * 8; i < 9 * CHN; i += 256 * 8)
        *(short8*)(wl + i) = *(const short8*)(wrow + i);
    int y = p / WP, x = p - (p / WP) * WP;
    int pn[9]; bool pv[9];
    #pragma unroll
    for (int k = 0; k < 9; k++) {
        int yy = y + k / 3 - 1, xx = x + (k % 3) - 1;
        pv[k] = (yy >= 0 && yy < HP && xx >= 0 && xx < WP);
        pn[k] = pv[k] ? yy * WP + xx : 0;
    }
    __syncthreads();
    for (int j = tid; j < 16 * 85; j += 256) {
        int bl = j / 85, c = (j - bl * 85) * 8;
        int b = b0 + bl;
        const unsigned short* hb = h1t + (size_t)b * P * CHN;
        float s1[8], s2[8];
        #pragma unroll
        for (int e = 0; e < 8; e++) { s1[e] = 0.f; s2[e] = 0.f; }
        #pragma unroll
        for (int k = 0; k < 9; k++) {
            if (!pv[k]) continue;
            const unsigned short* hr = hb + (size_t)pn[k] * CHN + c;
            short8 h1v = *(const short8*)hr;
            short8 h2v = *(const short8*)(hr + HID);
            short8 w1v = *(const short8*)(wl + k * CHN + c);
            short8 w2v = *(const short8*)(wl + k * CHN + HID + c);
            #pragma unroll
            for (int e = 0; e < 8; e++) {
                s1[e] += bf2f((unsigned short)w1v[e]) * bf2f((unsigned short)h1v[e]);
                s2[e] += bf2f((unsigned short)w2v[e]) * bf2f((unsigned short)h2v[e]);
            }
        }
        short8 o;
        #pragma unroll
        for (int e = 0; e < 8; e++) {
            float gl = 0.5f * s1[e] * (1.f + erff(s1[e] * 0.70710678118654752f));
            o[e] = (short)f2bf(gl * s2[e]);
        }
        *(short8*)(hgt + ((size_t)b * P + p) * KPAD + c) = o;
    }
    if (tid < 48) {
        int bl = tid / 3, z = (tid - bl * 3) * 8;
        *(short8*)(hgt + ((size_t)(b0 + bl) * P + p) * KPAD + HID + z) = (short8)0;
    }
}

// ---------------- tiled MFMA GEMM 2 (BK=64): out[m][n] = sum_k Wbout[m][k] hgt[n][k] ------
__global__ __launch_bounds__(256) void k_gemm_out(const unsigned short* __restrict__ A,
                                                  const unsigned short* __restrict__ B,
                                                  float* __restrict__ out) {
    __shared__ __align__(16) unsigned short As[64 * 64];     // 8 KB
    __shared__ __align__(16) unsigned short Bs[128 * 64];    // 16 KB
    int tid = threadIdx.x;
    int w = tid >> 6, lane = tid & 63, quad = lane >> 4, c16 = lane & 15;
    int m0 = blockIdx.x * 64, n0 = blockIdx.y * 128;
    int wm = (w & 1) * 32, wn = (w >> 1) * 64;
    f32x4 acc[2][4];
    #pragma unroll
    for (int i = 0; i < 2; i++)
        #pragma unroll
        for (int j = 0; j < 4; j++) acc[i][j] = (f32x4)0.f;

    for (int kc = 0; kc < 11; ++kc) {                        // K=704, chunks of 64
        int k0 = kc * 64;
        if (kc) __syncthreads();
        #pragma unroll
        for (int i = tid; i < 512; i += 256) {               // A: 64 rows x 8 pieces
            int r = i >> 3, s = i & 7, q = (s - (r >> 1)) & 7;
            gl2lds16(A + (size_t)(m0 + r) * KPAD + k0 + q * 8, As + (i & ~63) * 8);
        }
        #pragma unroll
        for (int i = tid; i < 1024; i += 256) {              // B: 128 rows x 8 pieces
            int r = i >> 3, s = i & 7, q = (s - (r >> 1)) & 7;
            gl2lds16(B + (size_t)(n0 + r) * KPAD + k0 + q * 8, Bs + (i & ~63) * 8);
        }
        __syncthreads();
        #pragma unroll
        for (int ks = 0; ks < 2; ++ks) {
            short8 af[2], bfr[4];
            #pragma unroll
            for (int i = 0; i < 2; i++) af[i] = fragld64(As, wm + i * 16 + c16, ks * 4 + quad);
            #pragma unroll
            for (int j = 0; j < 4; j++) bfr[j] = fragld64(Bs, wn + j * 16 + c16, ks * 4 + quad);
            #pragma unroll
            for (int i = 0; i < 2; i++)
                #pragma unroll
                for (int j = 0; j < 4; j++)
                    acc[i][j] = __builtin_amdgcn_mfma_f32_16x16x32_bf16(af[i], bfr[j], acc[i][j], 0, 0, 0);
        }
    }
    #pragma unroll
    for (int j = 0; j < 4; j++) {
        int n = n0 + wn + j * 16 + c16;
        int b = n / P, pp = n - b * P;
        #pragma unroll
        for (int i = 0; i < 2; i++) {
            int m = m0 + wm + i * 16 + quad * 4;
            #pragma unroll
            for (int r = 0; r < 4; r++)
                out[((size_t)b * DIMC + m + r) * P + pp] = acc[i][j][r];
        }
    }
}

extern "C" void kernel_launch(void* const* d_in, const int* in_sizes, int n_in,
                              void* d_out, int out_size, void* d_ws, size_t ws_size,
                              hipStream_t stream) {
    (void)in_sizes; (void)n_in; (void)out_size; (void)ws_size;
    const float* x     = (const float*)d_in[0];
    const float* W_in  = (const float*)d_in[1];
    const float* posi  = (const float*)d_in[2];
    const float* w0    = (const float*)d_in[3];
    const float* g0    = (const float*)d_in[4];
    const float* b0    = (const float*)d_in[5];
    const float* w1    = (const float*)d_in[6];
    const float* g1    = (const float*)d_in[7];
    const float* b1    = (const float*)d_in[8];
    const float* w2    = (const float*)d_in[9];
    const float* g2    = (const float*)d_in[10];
    const float* b2    = (const float*)d_in[11];
    const float* wf    = (const float*)d_in[12];
    const float* W_out = (const float*)d_in[13];
    float* out = (float*)d_out;
    char* ws = (char*)d_ws;

    unsigned short* Wbin  = (unsigned short*)(ws + OFS_WBIN);
    unsigned short* Wbout = (unsigned short*)(ws + OFS_WBOUT);
    unsigned short* Xt    = (unsigned short*)(ws + OFS_XT);
    float*          a_buf = (float*)(ws + OFS_ABUF);
    float*          v_buf = (float*)(ws + OFS_VBUF);
    unsigned short* wgtT  = (unsigned short*)(ws + OFS_WGTT);
    unsigned short* h1t   = (unsigned short*)(ws + OFS_H1T);
    unsigned short* hgt   = (unsigned short*)(ws + OFS_HGT);
    unsigned short* imc   = (unsigned short*)(ws + OFS_IMC);

    // casts / transposes
    k_casts<<<(NWIN + NWOUT + 255)/256, 256, 0, stream>>>(W_in, W_out, Wbin, Wbout);
    k_xt   <<<dim3(DIMC/32, BATCH), 256, 0, stream>>>(x, Xt);

    // weight-generator network
    k_stage0<<<1, 256, 0, stream>>>(posi, w0, g0, b0, a_buf);
    k_conv64<<<49, 256, 0, stream>>>(a_buf, w1, v_buf);
    k_lnrelu<<<1, 1024, 0, stream>>>(v_buf, g1, b1, a_buf);
    k_conv64<<<49, 256, 0, stream>>>(a_buf, w2, v_buf);
    k_lnrelu<<<1, 1024, 0, stream>>>(v_buf, g2, b2, a_buf);
    k_im2col<<<(P*KIM + 255)/256, 256, 0, stream>>>(a_buf, imc);
    k_gemm_wf<<<MTOT/64, 256, 0, stream>>>(wf, imc, wgtT);

    // main path (tiled MFMA, BK=64)
    k_gemm_in <<<dim3(MPADIN/128, (BATCH*P)/128), 256, 0, stream>>>(Wbin, Xt, h1t);
    k_tvg     <<<800, 256, 0, stream>>>(h1t, wgtT, hgt);
    k_gemm_out<<<dim3(DIMC/64, (BATCH*P)/128), 256, 0, stream>>>(Wbout, hgt, out);
}